// Round 2
// baseline (2156.427 us; speedup 1.0000x reference)
//
#include <hip/hip_runtime.h>
#include <math.h>

#define BQ 2
#define LQ 4096
#define DM 768
#define DI 1536
#define DS 16
#define DTR 48
#define E80 80   // DTR + 2*DS

// ---------------------------------------------------------------------------
// NT GEMM: C[m,n] = sum_k A[m,k]*B[n,k]; A,B row-major K-contiguous.
// 128x128 tile, BK=16, 256 threads, 8x8 microtile (split 4+4).
// ---------------------------------------------------------------------------
__global__ __launch_bounds__(256)
void gemm_nt(const float* __restrict__ A, const float* __restrict__ Bm,
             float* __restrict__ C,
             int M, int N, int K, long sA, long sB, long sC)
{
    __shared__ float As[16][132];
    __shared__ float Bs[16][132];
    const int b = blockIdx.z;
    const float* Ab = A + (long)b * sA;
    const float* Bb = Bm + (long)b * sB;
    float* Cb = C + (long)b * sC;
    const int m0 = blockIdx.y * 128, n0 = blockIdx.x * 128;
    const int tid = threadIdx.x;
    const int tm = tid >> 4, tn = tid & 15;

    float acc[8][8];
#pragma unroll
    for (int i = 0; i < 8; i++)
#pragma unroll
        for (int j = 0; j < 8; j++) acc[i][j] = 0.f;

    for (int k0 = 0; k0 < K; k0 += 16) {
#pragma unroll
        for (int i = 0; i < 2; i++) {
            int idx = tid + i * 256;          // 0..511
            int m = idx >> 2, kq = (idx & 3) * 4;
            float4 a = *(const float4*)&Ab[(long)(m0 + m) * K + k0 + kq];
            As[kq + 0][m] = a.x; As[kq + 1][m] = a.y;
            As[kq + 2][m] = a.z; As[kq + 3][m] = a.w;
            float4 bb = *(const float4*)&Bb[(long)(n0 + m) * K + k0 + kq];
            Bs[kq + 0][m] = bb.x; Bs[kq + 1][m] = bb.y;
            Bs[kq + 2][m] = bb.z; Bs[kq + 3][m] = bb.w;
        }
        __syncthreads();
#pragma unroll
        for (int k = 0; k < 16; k++) {
            float4 a0 = *(const float4*)&As[k][tm * 4];
            float4 a1 = *(const float4*)&As[k][64 + tm * 4];
            float4 b0 = *(const float4*)&Bs[k][tn * 4];
            float4 b1 = *(const float4*)&Bs[k][64 + tn * 4];
            float av[8] = {a0.x, a0.y, a0.z, a0.w, a1.x, a1.y, a1.z, a1.w};
            float bv[8] = {b0.x, b0.y, b0.z, b0.w, b1.x, b1.y, b1.z, b1.w};
#pragma unroll
            for (int i = 0; i < 8; i++)
#pragma unroll
                for (int j = 0; j < 8; j++)
                    acc[i][j] = fmaf(av[i], bv[j], acc[i][j]);
        }
        __syncthreads();
    }
#pragma unroll
    for (int i = 0; i < 8; i++) {
        int m = m0 + ((i < 4) ? (tm * 4 + i) : (64 + tm * 4 + i - 4));
        float4 c0 = {acc[i][0], acc[i][1], acc[i][2], acc[i][3]};
        float4 c1 = {acc[i][4], acc[i][5], acc[i][6], acc[i][7]};
        *(float4*)&Cb[(long)m * N + n0 + tn * 4]      = c0;
        *(float4*)&Cb[(long)m * N + n0 + 64 + tn * 4] = c1;
    }
}

// ---------------------------------------------------------------------------
// x_proj with fused depthwise-conv+SiLU recompute:
// dbl[br][b][l][e] = sum_d silu(conv(x))[d][l] * W[e][d], e in [0,80)
// ---------------------------------------------------------------------------
__global__ __launch_bounds__(256)
void xproj_kernel(const float* __restrict__ xz,
                  const float* __restrict__ cwa, const float* __restrict__ cba,
                  const float* __restrict__ cwb, const float* __restrict__ cbb,
                  const float* __restrict__ xpa, const float* __restrict__ xpb,
                  float* __restrict__ dbl)
{
    __shared__ float lw[80][68];
    __shared__ float lu[32][68];
    __shared__ float lraw[64][37];   // raw x, stride 37 (coprime 32)
    __shared__ float lcw[64][5];     // conv w[0..3] + bias[4]
    const int l0 = blockIdx.x * 32;
    const int b = blockIdx.y, br = blockIdx.z;
    const float* W  = br ? xpb : xpa;
    const float* CW = br ? cwb : cwa;
    const float* CB = br ? cbb : cba;
    const float* xb = xz + (long)b * 2 * DI * LQ;
    float* out = dbl + ((long)(br * BQ + b) * LQ + l0) * E80;
    const int tid = threadIdx.x;
    const int l = tid >> 3, eg = tid & 7;
    float acc[10];
#pragma unroll
    for (int i = 0; i < 10; i++) acc[i] = 0.f;

    for (int k0 = 0; k0 < DI; k0 += 64) {
        // stage x_proj weight tile: 80 x 64
#pragma unroll
        for (int i = 0; i < 5; i++) {
            int idx = tid + i * 256;          // 0..1279
            int e = idx >> 4, kq = (idx & 15) * 4;
            *(float4*)&lw[e][kq] = *(const float4*)&W[(long)e * DI + k0 + kq];
        }
        // stage conv weights + bias for these 64 channels
        {
            int dd = tid >> 2, k = tid & 3;
            lcw[dd][k] = CW[(k0 + dd) * 4 + k];
            if (tid < 64) lcw[tid][4] = CB[k0 + tid];
        }
        // stage raw x: 64 channels x 35 samples (l0-3 .. l0+31), reversed for br=1
        for (int i = tid; i < 64 * 35; i += 256) {
            int dd = i / 35, cc = i % 35;
            int src = l0 - 3 + cc;
            float v = 0.f;
            if (src >= 0 && src < LQ)
                v = xb[(long)(k0 + dd) * LQ + (br ? (LQ - 1 - src) : src)];
            lraw[dd][cc] = v;
        }
        __syncthreads();
        // compute u = silu(conv) into lu[l][d]
#pragma unroll
        for (int q = 0; q < 8; q++) {
            int o = tid + q * 256;            // 0..2047
            int dd = o & 63, ll = o >> 6;
            float a = lcw[dd][4];
            a = fmaf(lraw[dd][ll + 0], lcw[dd][0], a);
            a = fmaf(lraw[dd][ll + 1], lcw[dd][1], a);
            a = fmaf(lraw[dd][ll + 2], lcw[dd][2], a);
            a = fmaf(lraw[dd][ll + 3], lcw[dd][3], a);
            lu[ll][dd] = a * (1.f / (1.f + __expf(-a)));
        }
        __syncthreads();
        // accumulate
#pragma unroll
        for (int kk = 0; kk < 64; kk += 4) {
            float4 uv = *(const float4*)&lu[l][kk];
#pragma unroll
            for (int i = 0; i < 10; i++) {
                float4 wv = *(const float4*)&lw[eg * 10 + i][kk];
                acc[i] = fmaf(uv.x, wv.x, fmaf(uv.y, wv.y,
                         fmaf(uv.z, wv.z, fmaf(uv.w, wv.w, acc[i]))));
            }
        }
        __syncthreads();
    }
#pragma unroll
    for (int i = 0; i < 10; i++) out[(long)l * E80 + eg * 10 + i] = acc[i];
}

// ---------------------------------------------------------------------------
// Fused: conv+silu (u), dt_proj+softplus (delta), selective scan, gate,
// atomicAdd into y[b][l][d]. Block = 16 channels of one (br,b).
// Lane layout: 16 lanes (=states) per channel, 4 channels per wave.
// ---------------------------------------------------------------------------
__global__ __launch_bounds__(256)
void scan_kernel(const float* __restrict__ xz, const float* __restrict__ dbl,
                 const float* __restrict__ cwa, const float* __restrict__ cba,
                 const float* __restrict__ cwb, const float* __restrict__ cbb,
                 const float* __restrict__ dwa, const float* __restrict__ dwb,
                 const float* __restrict__ dba, const float* __restrict__ dbb,
                 const float* __restrict__ Ala, const float* __restrict__ Alb,
                 const float* __restrict__ Da, const float* __restrict__ Db,
                 float* __restrict__ y)
{
    __shared__ float s_x[16][68];    // raw x (t0-3 .. t0+64)
    __shared__ float s_z[16][68];
    __shared__ float s_u[16][68];
    __shared__ float s_dl[16][68];
    __shared__ float s_dt[64][49];   // dt_low tile, stride 49 (coprime 32)
    __shared__ float s_B[64][16];
    __shared__ float s_C[64][16];
    __shared__ float s_y[16][65];
    __shared__ float s_wd[16][49];   // dt_proj rows
    __shared__ float s_cw[16][5];    // conv w + bias
    __shared__ float s_db[16];       // dt bias

    const int d0 = blockIdx.x * 16;
    const int b = blockIdx.y, br = blockIdx.z;
    const int tid = threadIdx.x;
    const int lane = tid & 63, wid = tid >> 6;
    const int c = wid * 4 + (lane >> 4);   // channel in block [0,16)
    const int n = lane & 15;               // state index
    const int d = d0 + c;
    const float An = -__expf((br ? Alb : Ala)[d * 16 + n]);
    const float Dd = (br ? Db : Da)[d];
    const float* xb   = xz + ((long)b * 2 * DI) * LQ;
    const float* zb   = xz + ((long)b * 2 * DI + DI) * LQ;
    const float* dblb = dbl + (long)(br * BQ + b) * LQ * E80;
    const float* DW  = br ? dwb : dwa;
    const float* DBi = br ? dbb : dba;
    const float* CW  = br ? cwb : cwa;
    const float* CB  = br ? cbb : cba;
    float* yo = y + (long)b * LQ * DI;

    // one-time stages
    for (int i = tid; i < 16 * 48; i += 256) {
        int cc = i / 48, k = i % 48;
        s_wd[cc][k] = DW[(d0 + cc) * 48 + k];
    }
    if (tid < 64) { int cc = tid >> 2, k = tid & 3; s_cw[cc][k] = CW[(d0 + cc) * 4 + k]; }
    if (tid < 16) { s_cw[tid][4] = CB[d0 + tid]; s_db[tid] = DBi[d0 + tid]; }

    float h = 0.f;
    const int zc = tid >> 4, zi = (tid & 15) * 4;

    for (int t0 = 0; t0 < LQ; t0 += 64) {
        // ---- stage z (vectorized; reversed for br=1)
        if (br == 0) {
            *(float4*)&s_z[zc][zi] = *(const float4*)&zb[(long)(d0 + zc) * LQ + t0 + zi];
        } else {
            float4 zv = *(const float4*)&zb[(long)(d0 + zc) * LQ + (LQ - 4 - t0 - zi)];
            s_z[zc][zi + 0] = zv.w; s_z[zc][zi + 1] = zv.z;
            s_z[zc][zi + 2] = zv.y; s_z[zc][zi + 3] = zv.x;
        }
        // ---- stage raw x: 16 x 68 scalars (t0-3+i), reversed for br=1
        {
            int cc = tid >> 4, base = tid & 15;
#pragma unroll
            for (int q = 0; q < 4; q++) {
                int i = base + q * 16;
                int src = t0 - 3 + i;
                float v = 0.f;
                if (src >= 0 && src < LQ)
                    v = xb[(long)(d0 + cc) * LQ + (br ? (LQ - 1 - src) : src)];
                s_x[cc][i] = v;
            }
            if (base < 4) {
                int i = 64 + base;
                int src = t0 - 3 + i;
                float v = 0.f;
                if (src >= 0 && src < LQ)
                    v = xb[(long)(d0 + cc) * LQ + (br ? (LQ - 1 - src) : src)];
                s_x[cc][i] = v;
            }
        }
        // ---- stage dt_low tile: 64 x 48
        for (int f = tid; f < 768; f += 256) {
            int t = f / 12, q = f % 12;
            float4 v = *(const float4*)&dblb[(long)(t0 + t) * E80 + q * 4];
            s_dt[t][q * 4 + 0] = v.x; s_dt[t][q * 4 + 1] = v.y;
            s_dt[t][q * 4 + 2] = v.z; s_dt[t][q * 4 + 3] = v.w;
        }
        // ---- stage B, C
#pragma unroll
        for (int i2 = 0; i2 < 2; i2++) {
            int f = tid + i2 * 256;
            int trow = f >> 3, eq = f & 7;
            float4 v = *(const float4*)&dblb[(long)(t0 + trow) * E80 + 48 + eq * 4];
            if (eq < 4) *(float4*)&s_B[trow][eq * 4] = v;
            else        *(float4*)&s_C[trow][(eq - 4) * 4] = v;
        }
        __syncthreads();
        // ---- phase A: compute u (conv+silu) and delta (dot+softplus)
#pragma unroll
        for (int q = 0; q < 4; q++) {
            int p = tid + q * 256;
            int cc = p >> 6, t = p & 63;
            float a = s_cw[cc][4];
            a = fmaf(s_x[cc][t + 0], s_cw[cc][0], a);
            a = fmaf(s_x[cc][t + 1], s_cw[cc][1], a);
            a = fmaf(s_x[cc][t + 2], s_cw[cc][2], a);
            a = fmaf(s_x[cc][t + 3], s_cw[cc][3], a);
            s_u[cc][t] = a * (1.f / (1.f + __expf(-a)));
            float da = s_db[cc];
#pragma unroll
            for (int k = 0; k < 48; k++) da = fmaf(s_dt[t][k], s_wd[cc][k], da);
            s_dl[cc][t] = (da > 20.f) ? da : log1pf(__expf(da));
        }
        __syncthreads();
        // ---- phase B: sequential scan over 64 steps
#pragma unroll 4
        for (int j = 0; j < 64; j++) {
            float dl = s_dl[c][j];
            float uu = s_u[c][j];
            float dA = __expf(dl * An);
            h = fmaf(dA, h, (dl * uu) * s_B[j][n]);
            float p = h * s_C[j][n];
            p += __shfl_xor(p, 1);
            p += __shfl_xor(p, 2);
            p += __shfl_xor(p, 4);
            p += __shfl_xor(p, 8);
            if (n == 0) s_y[c][j] = fmaf(uu, Dd, p);
        }
        __syncthreads();
        // ---- phase C: gate + atomic accumulate into y[b][l_orig][d]
#pragma unroll
        for (int w2 = 0; w2 < 4; w2++) {
            int cell = tid + w2 * 256;
            int t = cell >> 4, dd = cell & 15;
            float yv = s_y[dd][t];
            float zv = s_z[dd][t];
            float g = zv * (1.f / (1.f + __expf(-zv)));
            int lorig = br ? (LQ - 1 - (t0 + t)) : (t0 + t);
            atomicAdd(&yo[(long)lorig * DI + d0 + dd], yv * g);
        }
        __syncthreads();
    }
}

// ---------------------------------------------------------------------------
extern "C" void kernel_launch(void* const* d_in, const int* in_sizes, int n_in,
                              void* d_out, int out_size, void* d_ws, size_t ws_size,
                              hipStream_t stream)
{
    const float* hs  = (const float*)d_in[0];
    const float* Wi  = (const float*)d_in[1];
    const float* Wo  = (const float*)d_in[2];
    const float* cwa = (const float*)d_in[3];
    const float* cba = (const float*)d_in[4];
    const float* cwb = (const float*)d_in[5];
    const float* cbb = (const float*)d_in[6];
    const float* xpa = (const float*)d_in[7];
    const float* xpb = (const float*)d_in[8];
    const float* dwa = (const float*)d_in[9];
    const float* dwb = (const float*)d_in[10];
    const float* dba = (const float*)d_in[11];
    const float* dbb = (const float*)d_in[12];
    const float* Ala = (const float*)d_in[13];
    const float* Alb = (const float*)d_in[14];
    const float* Da  = (const float*)d_in[15];
    const float* Db  = (const float*)d_in[16];
    float* out = (float*)d_out;

    float* ws  = (float*)d_ws;
    float* xz  = ws;                                  // [B][3072][L]   25,165,824 f
    float* dbl = xz  + (size_t)25165824;              // [2][B][L][80]   1,310,720 f
    float* y   = dbl + (size_t)1310720;               // [B][L][DI]     12,582,912 f
    // total: 39,059,456 floats = 156.2 MB

    // 0) zero the shared y accumulator (ws is poisoned before every launch)
    hipMemsetAsync(y, 0, (size_t)BQ * LQ * DI * sizeof(float), stream);
    // 1) in_proj: xz[b,e,l] = sum_d hs[b,l,d]*Wi[e,d]
    gemm_nt<<<dim3(32, 24, 2), 256, 0, stream>>>(
        Wi, hs, xz, 2 * DI, LQ, DM, 0, (long)LQ * DM, (long)2 * DI * LQ);
    // 2) x_proj (conv+silu recomputed on the fly)
    xproj_kernel<<<dim3(128, 2, 2), 256, 0, stream>>>(
        xz, cwa, cba, cwb, cbb, xpa, xpb, dbl);
    // 3) fused conv+delta+scan+gate, atomic add into y
    scan_kernel<<<dim3(96, 2, 2), 256, 0, stream>>>(
        xz, dbl, cwa, cba, cwb, cbb, dwa, dwb, dba, dbb, Ala, Alb, Da, Db, y);
    // 4) out_proj
    gemm_nt<<<dim3(6, 32, 2), 256, 0, stream>>>(
        y, Wo, out, LQ, DM, DI, (long)LQ * DI, 0, (long)LQ * DM);
}

// Round 3
// 1431.050 us; speedup vs baseline: 1.5069x; 1.5069x over previous
//
#include <hip/hip_runtime.h>
#include <math.h>

#define BQ 2
#define LQ 4096
#define DM 768
#define DI 1536
#define DS 16
#define E80 80   // DTR + 2*DS
#define NC 32
#define CH 128   // LQ / NC

__device__ __forceinline__ float bf2f(ushort u) { return __uint_as_float(((unsigned)u) << 16); }
__device__ __forceinline__ ushort f2bf(float x) {
    unsigned u = __float_as_uint(x);
    unsigned r = (u + 0x7fffu + ((u >> 16) & 1u)) >> 16;
    return (ushort)r;
}

// ---------------------------------------------------------------------------
// NT GEMM (fp32): C[m,n] = sum_k A[m,k]*B[n,k]. 128x128 tile, BK=16.
// Used for in_proj.
// ---------------------------------------------------------------------------
__global__ __launch_bounds__(256)
void gemm_nt(const float* __restrict__ A, const float* __restrict__ Bm,
             float* __restrict__ C,
             int M, int N, int K, long sA, long sB, long sC)
{
    __shared__ float As[16][132];
    __shared__ float Bs[16][132];
    const int b = blockIdx.z;
    const float* Ab = A + (long)b * sA;
    const float* Bb = Bm + (long)b * sB;
    float* Cb = C + (long)b * sC;
    const int m0 = blockIdx.y * 128, n0 = blockIdx.x * 128;
    const int tid = threadIdx.x;
    const int tm = tid >> 4, tn = tid & 15;

    float acc[8][8];
#pragma unroll
    for (int i = 0; i < 8; i++)
#pragma unroll
        for (int j = 0; j < 8; j++) acc[i][j] = 0.f;

    for (int k0 = 0; k0 < K; k0 += 16) {
#pragma unroll
        for (int i = 0; i < 2; i++) {
            int idx = tid + i * 256;
            int m = idx >> 2, kq = (idx & 3) * 4;
            float4 a = *(const float4*)&Ab[(long)(m0 + m) * K + k0 + kq];
            As[kq + 0][m] = a.x; As[kq + 1][m] = a.y;
            As[kq + 2][m] = a.z; As[kq + 3][m] = a.w;
            float4 bb = *(const float4*)&Bb[(long)(n0 + m) * K + k0 + kq];
            Bs[kq + 0][m] = bb.x; Bs[kq + 1][m] = bb.y;
            Bs[kq + 2][m] = bb.z; Bs[kq + 3][m] = bb.w;
        }
        __syncthreads();
#pragma unroll
        for (int k = 0; k < 16; k++) {
            float4 a0 = *(const float4*)&As[k][tm * 4];
            float4 a1 = *(const float4*)&As[k][64 + tm * 4];
            float4 b0 = *(const float4*)&Bs[k][tn * 4];
            float4 b1 = *(const float4*)&Bs[k][64 + tn * 4];
            float av[8] = {a0.x, a0.y, a0.z, a0.w, a1.x, a1.y, a1.z, a1.w};
            float bv[8] = {b0.x, b0.y, b0.z, b0.w, b1.x, b1.y, b1.z, b1.w};
#pragma unroll
            for (int i = 0; i < 8; i++)
#pragma unroll
                for (int j = 0; j < 8; j++)
                    acc[i][j] = fmaf(av[i], bv[j], acc[i][j]);
        }
        __syncthreads();
    }
#pragma unroll
    for (int i = 0; i < 8; i++) {
        int m = m0 + ((i < 4) ? (tm * 4 + i) : (64 + tm * 4 + i - 4));
        float4 c0 = {acc[i][0], acc[i][1], acc[i][2], acc[i][3]};
        float4 c1 = {acc[i][4], acc[i][5], acc[i][6], acc[i][7]};
        *(float4*)&Cb[(long)m * N + n0 + tn * 4]      = c0;
        *(float4*)&Cb[(long)m * N + n0 + 64 + tn * 4] = c1;
    }
}

// ---------------------------------------------------------------------------
// x_proj with fused conv+SiLU recompute; also emits u_t (bf16, [z][l][d]).
// ---------------------------------------------------------------------------
__global__ __launch_bounds__(256)
void xproj_kernel(const float* __restrict__ xz,
                  const float* __restrict__ cwa, const float* __restrict__ cba,
                  const float* __restrict__ cwb, const float* __restrict__ cbb,
                  const float* __restrict__ xpa, const float* __restrict__ xpb,
                  float* __restrict__ dbl, ushort* __restrict__ ut)
{
    __shared__ float lw[80][68];
    __shared__ float lu[32][68];
    __shared__ float lraw[64][37];
    __shared__ float lcw[64][5];
    const int l0 = blockIdx.x * 32;
    const int b = blockIdx.y, br = blockIdx.z;
    const int z = br * BQ + b;
    const float* W  = br ? xpb : xpa;
    const float* CW = br ? cwb : cwa;
    const float* CB = br ? cbb : cba;
    const float* xb = xz + (long)b * 2 * DI * LQ;
    float* out = dbl + ((long)z * LQ + l0) * E80;
    const int tid = threadIdx.x;
    const int l = tid >> 3, eg = tid & 7;
    float acc[10];
#pragma unroll
    for (int i = 0; i < 10; i++) acc[i] = 0.f;

    for (int k0 = 0; k0 < DI; k0 += 64) {
#pragma unroll
        for (int i = 0; i < 5; i++) {
            int idx = tid + i * 256;
            int e = idx >> 4, kq = (idx & 15) * 4;
            *(float4*)&lw[e][kq] = *(const float4*)&W[(long)e * DI + k0 + kq];
        }
        {
            int dd = tid >> 2, k = tid & 3;
            lcw[dd][k] = CW[(k0 + dd) * 4 + k];
            if (tid < 64) lcw[tid][4] = CB[k0 + tid];
        }
        for (int i = tid; i < 64 * 35; i += 256) {
            int dd = i / 35, cc = i % 35;
            int src = l0 - 3 + cc;
            float v = 0.f;
            if (src >= 0 && src < LQ)
                v = xb[(long)(k0 + dd) * LQ + (br ? (LQ - 1 - src) : src)];
            lraw[dd][cc] = v;
        }
        __syncthreads();
#pragma unroll
        for (int q = 0; q < 8; q++) {
            int o = tid + q * 256;
            int dd = o & 63, ll = o >> 6;
            float a = lcw[dd][4];
            a = fmaf(lraw[dd][ll + 0], lcw[dd][0], a);
            a = fmaf(lraw[dd][ll + 1], lcw[dd][1], a);
            a = fmaf(lraw[dd][ll + 2], lcw[dd][2], a);
            a = fmaf(lraw[dd][ll + 3], lcw[dd][3], a);
            float uu = a * (1.f / (1.f + __expf(-a)));
            lu[ll][dd] = uu;
            ut[((long)z * LQ + l0 + ll) * DI + k0 + dd] = f2bf(uu);
        }
        __syncthreads();
#pragma unroll
        for (int kk = 0; kk < 64; kk += 4) {
            float4 uv = *(const float4*)&lu[l][kk];
#pragma unroll
            for (int i = 0; i < 10; i++) {
                float4 wv = *(const float4*)&lw[eg * 10 + i][kk];
                acc[i] = fmaf(uv.x, wv.x, fmaf(uv.y, wv.y,
                         fmaf(uv.z, wv.z, fmaf(uv.w, wv.w, acc[i]))));
            }
        }
        __syncthreads();
    }
#pragma unroll
    for (int i = 0; i < 10; i++) out[(long)l * E80 + eg * 10 + i] = acc[i];
}

// ---------------------------------------------------------------------------
// Transpose z-half of xz [b][DI..2DI][l] -> z_t bf16 [b][l][d].
// ---------------------------------------------------------------------------
__global__ __launch_bounds__(256)
void transpose_z(const float* __restrict__ xz, ushort* __restrict__ zt)
{
    __shared__ float t[64][65];
    const int l0 = blockIdx.x * 64, d0 = blockIdx.y * 64, b = blockIdx.z;
    const float* src = xz + ((long)b * 2 * DI + DI + d0) * LQ + l0;
    const int tid = threadIdx.x;
    const int r = tid >> 4, c4 = (tid & 15) * 4;
#pragma unroll
    for (int i = 0; i < 4; i++) {
        float4 v = *(const float4*)&src[(long)(r + i * 16) * LQ + c4];
        t[c4 + 0][r + i * 16] = v.x; t[c4 + 1][r + i * 16] = v.y;
        t[c4 + 2][r + i * 16] = v.z; t[c4 + 3][r + i * 16] = v.w;
    }
    __syncthreads();
    const int l = tid >> 2, seg = (tid & 3) * 16;
    ushort tmp[16];
#pragma unroll
    for (int j = 0; j < 16; j++) tmp[j] = f2bf(t[l][seg + j]);
    uint4 p0, p1;
    p0.x = tmp[0] | (tmp[1] << 16);  p0.y = tmp[2] | (tmp[3] << 16);
    p0.z = tmp[4] | (tmp[5] << 16);  p0.w = tmp[6] | (tmp[7] << 16);
    p1.x = tmp[8] | (tmp[9] << 16);  p1.y = tmp[10] | (tmp[11] << 16);
    p1.z = tmp[12] | (tmp[13] << 16); p1.w = tmp[14] | (tmp[15] << 16);
    ushort* dst = zt + ((long)b * LQ + l0 + l) * DI + d0 + seg;
    *(uint4*)dst = p0;
    *(uint4*)(dst + 8) = p1;
}

// ---------------------------------------------------------------------------
// delta GEMM: dl_t[z][t][d] = softplus(dot48(dbl[z][t][0:48], W[d]) + bias[d])
// bf16 output, [t][d] layout. Block: 64 t x 256 d.
// ---------------------------------------------------------------------------
__global__ __launch_bounds__(256)
void delta_kernel(const float* __restrict__ dbl,
                  const float* __restrict__ dwa, const float* __restrict__ dwb,
                  const float* __restrict__ dba, const float* __restrict__ dbb,
                  ushort* __restrict__ dlt)
{
    __shared__ float sdt[64][49];
    const int t0 = blockIdx.x * 64;
    const int d = blockIdx.y * 256 + threadIdx.x;
    const int z = blockIdx.z;
    const float* W    = (z >> 1) ? dwb : dwa;
    const float* bias = (z >> 1) ? dbb : dba;
    const float* dblb = dbl + (long)z * LQ * E80;

    float w[48];
#pragma unroll
    for (int i = 0; i < 12; i++) {
        float4 v = *(const float4*)&W[(long)d * 48 + i * 4];
        w[i * 4] = v.x; w[i * 4 + 1] = v.y; w[i * 4 + 2] = v.z; w[i * 4 + 3] = v.w;
    }
    const float bi = bias[d];
    for (int f = threadIdx.x; f < 768; f += 256) {
        int t = f / 12, q = f % 12;
        float4 v = *(const float4*)&dblb[(long)(t0 + t) * E80 + q * 4];
        sdt[t][q * 4 + 0] = v.x; sdt[t][q * 4 + 1] = v.y;
        sdt[t][q * 4 + 2] = v.z; sdt[t][q * 4 + 3] = v.w;
    }
    __syncthreads();
    for (int t = 0; t < 64; t++) {
        float a = bi;
#pragma unroll
        for (int k = 0; k < 48; k++) a = fmaf(sdt[t][k], w[k], a);
        float sp = (a > 20.f) ? a : log1pf(__expf(a));
        dlt[((long)z * LQ + t0 + t) * DI + d] = f2bf(sp);
    }
}

// ---------------------------------------------------------------------------
// Scan pass 1: per-chunk summaries. Lane = one channel, 16 states in VGPRs.
// Outputs: Sdl[z][c][d] = sum(delta), Hloc[z][c][d][n] = local chunk-end h.
// ---------------------------------------------------------------------------
__global__ __launch_bounds__(256)
void scan_p1(const ushort* __restrict__ ut, const ushort* __restrict__ dlt,
             const float* __restrict__ dbl,
             const float* __restrict__ Ala, const float* __restrict__ Alb,
             float* __restrict__ Sdl, float* __restrict__ Hloc)
{
    const int d = blockIdx.x * 256 + threadIdx.x;
    const int c = blockIdx.y;
    const int z = blockIdx.z;
    const int br = z >> 1;
    const float* Al = br ? Alb : Ala;
    float An[16];
#pragma unroll
    for (int i = 0; i < 4; i++) {
        float4 v = *(const float4*)&Al[(long)d * 16 + i * 4];
        An[i * 4] = -__expf(v.x); An[i * 4 + 1] = -__expf(v.y);
        An[i * 4 + 2] = -__expf(v.z); An[i * 4 + 3] = -__expf(v.w);
    }
    const long lbase = (long)z * LQ + (long)c * CH;
    const ushort* ub = ut + lbase * DI + d;
    const ushort* db = dlt + lbase * DI + d;
    const float* bc = dbl + lbase * E80 + 48;

    float h[16];
#pragma unroll
    for (int n = 0; n < 16; n++) h[n] = 0.f;
    float sdl = 0.f;

    for (int t0 = 0; t0 < CH; t0 += 8) {
        ushort uu[8], dd[8];
#pragma unroll
        for (int j = 0; j < 8; j++) {
            uu[j] = ub[(long)(t0 + j) * DI];
            dd[j] = db[(long)(t0 + j) * DI];
        }
#pragma unroll
        for (int j = 0; j < 8; j++) {
            float dl = bf2f(dd[j]);
            float u  = bf2f(uu[j]);
            sdl += dl;
            float du = dl * u;
            const float* Bp = bc + (long)(t0 + j) * E80;
            float Bv[16];
#pragma unroll
            for (int i = 0; i < 4; i++) {
                float4 v = *(const float4*)&Bp[i * 4];
                Bv[i * 4] = v.x; Bv[i * 4 + 1] = v.y;
                Bv[i * 4 + 2] = v.z; Bv[i * 4 + 3] = v.w;
            }
#pragma unroll
            for (int n = 0; n < 16; n++)
                h[n] = fmaf(__expf(dl * An[n]), h[n], du * Bv[n]);
        }
    }
    Sdl[((long)z * NC + c) * DI + d] = sdl;
    float* Hp = Hloc + (((long)z * NC + c) * DI + d) * 16;
#pragma unroll
    for (int i = 0; i < 4; i++)
        *(float4*)&Hp[i * 4] = make_float4(h[i * 4], h[i * 4 + 1], h[i * 4 + 2], h[i * 4 + 3]);
}

// ---------------------------------------------------------------------------
// Scan pass 2: inter-chunk scan. Thread = (d,n). h0[z][c][d][n] = h entering c.
// ---------------------------------------------------------------------------
__global__ __launch_bounds__(256)
void scan_p2(const float* __restrict__ Sdl, const float* __restrict__ Hloc,
             const float* __restrict__ Ala, const float* __restrict__ Alb,
             float* __restrict__ h0)
{
    const int idx = blockIdx.x * 256 + threadIdx.x;   // 0 .. DI*16-1
    const int z = blockIdx.y;
    const int d = idx >> 4, n = idx & 15;
    const float* Al = (z >> 1) ? Alb : Ala;
    const float An = -__expf(Al[(long)d * 16 + n]);
    float h = 0.f;
    for (int c = 0; c < NC; c++) {
        h0[((long)z * NC + c) * DI * 16 + idx] = h;
        float sdl = Sdl[((long)z * NC + c) * DI + d];
        float Hl = Hloc[((long)z * NC + c) * DI * 16 + idx];
        h = fmaf(__expf(An * sdl), h, Hl);
    }
}

// ---------------------------------------------------------------------------
// Scan pass 3: re-run chunks from correct h0, emit y (+D term) as bf16 [l][d].
// Branch B written pre-flipped so ya+yb align in original l.
// ---------------------------------------------------------------------------
__global__ __launch_bounds__(256)
void scan_p3(const ushort* __restrict__ ut, const ushort* __restrict__ dlt,
             const float* __restrict__ dbl, const float* __restrict__ h0,
             const float* __restrict__ Ala, const float* __restrict__ Alb,
             const float* __restrict__ Da, const float* __restrict__ Db,
             ushort* __restrict__ ya, ushort* __restrict__ yb)
{
    const int d = blockIdx.x * 256 + threadIdx.x;
    const int c = blockIdx.y;
    const int z = blockIdx.z;
    const int br = z >> 1, b = z & 1;
    const float* Al = br ? Alb : Ala;
    float An[16];
#pragma unroll
    for (int i = 0; i < 4; i++) {
        float4 v = *(const float4*)&Al[(long)d * 16 + i * 4];
        An[i * 4] = -__expf(v.x); An[i * 4 + 1] = -__expf(v.y);
        An[i * 4 + 2] = -__expf(v.z); An[i * 4 + 3] = -__expf(v.w);
    }
    const float Dd = (br ? Db : Da)[d];
    const long lbase = (long)z * LQ + (long)c * CH;
    const ushort* ub = ut + lbase * DI + d;
    const ushort* db = dlt + lbase * DI + d;
    const float* bc = dbl + lbase * E80 + 48;
    const float* Hp = h0 + (((long)z * NC + c) * DI + d) * 16;
    float h[16];
#pragma unroll
    for (int i = 0; i < 4; i++) {
        float4 v = *(const float4*)&Hp[i * 4];
        h[i * 4] = v.x; h[i * 4 + 1] = v.y; h[i * 4 + 2] = v.z; h[i * 4 + 3] = v.w;
    }
    ushort* yo = br ? yb : ya;

    for (int t0 = 0; t0 < CH; t0 += 8) {
        ushort uu[8], dd[8];
#pragma unroll
        for (int j = 0; j < 8; j++) {
            uu[j] = ub[(long)(t0 + j) * DI];
            dd[j] = db[(long)(t0 + j) * DI];
        }
#pragma unroll
        for (int j = 0; j < 8; j++) {
            float dl = bf2f(dd[j]);
            float u  = bf2f(uu[j]);
            float du = dl * u;
            const float* Bp = bc + (long)(t0 + j) * E80;
            float Bv[16], Cv[16];
#pragma unroll
            for (int i = 0; i < 4; i++) {
                float4 v = *(const float4*)&Bp[i * 4];
                Bv[i * 4] = v.x; Bv[i * 4 + 1] = v.y;
                Bv[i * 4 + 2] = v.z; Bv[i * 4 + 3] = v.w;
                float4 w2 = *(const float4*)&Bp[16 + i * 4];
                Cv[i * 4] = w2.x; Cv[i * 4 + 1] = w2.y;
                Cv[i * 4 + 2] = w2.z; Cv[i * 4 + 3] = w2.w;
            }
            float y = u * Dd;
#pragma unroll
            for (int n = 0; n < 16; n++) {
                h[n] = fmaf(__expf(dl * An[n]), h[n], du * Bv[n]);
                y = fmaf(h[n], Cv[n], y);
            }
            int t = c * CH + t0 + j;
            long lorig = br ? (LQ - 1 - t) : t;
            yo[((long)b * LQ + lorig) * DI + d] = f2bf(y);
        }
    }
}

// ---------------------------------------------------------------------------
// out_proj GEMM with fused A = (ya + yb) * silu(z_t), all bf16 [l][d].
// out[b][l][o] = sum_d A[l][d] * Wo[o][d].
// ---------------------------------------------------------------------------
__global__ __launch_bounds__(256)
void gemm_out(const ushort* __restrict__ ya, const ushort* __restrict__ yb,
              const ushort* __restrict__ zt, const float* __restrict__ Wo,
              float* __restrict__ C)
{
    __shared__ float As[16][132];
    __shared__ float Bs[16][132];
    const int b = blockIdx.z;
    const int m0 = blockIdx.y * 128, n0 = blockIdx.x * 128;
    const int tid = threadIdx.x;
    const int tm = tid >> 4, tn = tid & 15;
    float* Cb = C + (long)b * LQ * DM;

    float acc[8][8];
#pragma unroll
    for (int i = 0; i < 8; i++)
#pragma unroll
        for (int j = 0; j < 8; j++) acc[i][j] = 0.f;

    const int am = tid >> 1, akg = (tid & 1) * 8;
    for (int k0 = 0; k0 < DI; k0 += 16) {
        {
            long off = ((long)b * LQ + m0 + am) * DI + k0 + akg;
            uint4 pa = *(const uint4*)(ya + off);
            uint4 pb = *(const uint4*)(yb + off);
            uint4 pz = *(const uint4*)(zt + off);
            unsigned wa[4] = {pa.x, pa.y, pa.z, pa.w};
            unsigned wb[4] = {pb.x, pb.y, pb.z, pb.w};
            unsigned wz[4] = {pz.x, pz.y, pz.z, pz.w};
#pragma unroll
            for (int q = 0; q < 4; q++) {
                float y0 = __uint_as_float(wa[q] << 16) + __uint_as_float(wb[q] << 16);
                float y1 = __uint_as_float(wa[q] & 0xffff0000u) + __uint_as_float(wb[q] & 0xffff0000u);
                float z0 = __uint_as_float(wz[q] << 16);
                float z1 = __uint_as_float(wz[q] & 0xffff0000u);
                As[akg + q * 2 + 0][am] = y0 * (z0 / (1.f + __expf(-z0)));
                As[akg + q * 2 + 1][am] = y1 * (z1 / (1.f + __expf(-z1)));
            }
        }
#pragma unroll
        for (int i = 0; i < 2; i++) {
            int idx = tid + i * 256;
            int m = idx >> 2, kq = (idx & 3) * 4;
            float4 bb = *(const float4*)&Wo[(long)(n0 + m) * DI + k0 + kq];
            Bs[kq + 0][m] = bb.x; Bs[kq + 1][m] = bb.y;
            Bs[kq + 2][m] = bb.z; Bs[kq + 3][m] = bb.w;
        }
        __syncthreads();
#pragma unroll
        for (int k = 0; k < 16; k++) {
            float4 a0 = *(const float4*)&As[k][tm * 4];
            float4 a1 = *(const float4*)&As[k][64 + tm * 4];
            float4 b0 = *(const float4*)&Bs[k][tn * 4];
            float4 b1 = *(const float4*)&Bs[k][64 + tn * 4];
            float av[8] = {a0.x, a0.y, a0.z, a0.w, a1.x, a1.y, a1.z, a1.w};
            float bv[8] = {b0.x, b0.y, b0.z, b0.w, b1.x, b1.y, b1.z, b1.w};
#pragma unroll
            for (int i = 0; i < 8; i++)
#pragma unroll
                for (int j = 0; j < 8; j++)
                    acc[i][j] = fmaf(av[i], bv[j], acc[i][j]);
        }
        __syncthreads();
    }
#pragma unroll
    for (int i = 0; i < 8; i++) {
        int m = m0 + ((i < 4) ? (tm * 4 + i) : (64 + tm * 4 + i - 4));
        float4 c0 = {acc[i][0], acc[i][1], acc[i][2], acc[i][3]};
        float4 c1 = {acc[i][4], acc[i][5], acc[i][6], acc[i][7]};
        *(float4*)&Cb[(long)m * DM + n0 + tn * 4]      = c0;
        *(float4*)&Cb[(long)m * DM + n0 + 64 + tn * 4] = c1;
    }
}

// ---------------------------------------------------------------------------
extern "C" void kernel_launch(void* const* d_in, const int* in_sizes, int n_in,
                              void* d_out, int out_size, void* d_ws, size_t ws_size,
                              hipStream_t stream)
{
    const float* hs  = (const float*)d_in[0];
    const float* Wi  = (const float*)d_in[1];
    const float* Wo  = (const float*)d_in[2];
    const float* cwa = (const float*)d_in[3];
    const float* cba = (const float*)d_in[4];
    const float* cwb = (const float*)d_in[5];
    const float* cbb = (const float*)d_in[6];
    const float* xpa = (const float*)d_in[7];
    const float* xpb = (const float*)d_in[8];
    const float* dwa = (const float*)d_in[9];
    const float* dwb = (const float*)d_in[10];
    const float* dba = (const float*)d_in[11];
    const float* dbb = (const float*)d_in[12];
    const float* Ala = (const float*)d_in[13];
    const float* Alb = (const float*)d_in[14];
    const float* Da  = (const float*)d_in[15];
    const float* Db  = (const float*)d_in[16];
    float* out = (float*)d_out;

    float* ws = (float*)d_ws;
    // Region A (xz, fp32, dies after transpose_z) is reused for dl_t + ya + yb.
    float*  xz   = ws;                                  // 25,165,824 f
    ushort* dl_t = (ushort*)ws;                         // 25,165,824 bf16 (12,582,912 f)
    ushort* ya   = (ushort*)(ws + 12582912);            // 12,582,912 bf16 (6,291,456 f)
    ushort* yb   = (ushort*)(ws + 18874368);            // 12,582,912 bf16 (6,291,456 f)
    float*  dbl  = ws + 25165824;                       //  1,310,720 f
    ushort* u_t  = (ushort*)(ws + 26476544);            // 25,165,824 bf16 (12,582,912 f)
    ushort* z_t  = (ushort*)(ws + 39059456);            // 12,582,912 bf16 ( 6,291,456 f)
    float*  Sdl  = ws + 45350912;                       //    196,608 f
    float*  Hloc = ws + 45547520;                       //  3,145,728 f
    float*  h0   = ws + 48693248;                       //  3,145,728 f
    // total 51,838,976 floats = 207.4 MB

    // 1) in_proj: xz[b,e,l] = sum_d hs[b,l,d]*Wi[e,d]
    gemm_nt<<<dim3(32, 24, 2), 256, 0, stream>>>(
        Wi, hs, xz, 2 * DI, LQ, DM, 0, (long)LQ * DM, (long)2 * DI * LQ);
    // 2) x_proj (+ u_t bf16 emit)
    xproj_kernel<<<dim3(128, 2, 2), 256, 0, stream>>>(
        xz, cwa, cba, cwb, cbb, xpa, xpb, dbl, u_t);
    // 3) z transpose to bf16 [l][d]   (last reader of xz)
    transpose_z<<<dim3(64, 24, 2), 256, 0, stream>>>(xz, z_t);
    // 4) delta = softplus(dt_proj(dt_low)+bias), bf16 [t][d]  (overwrites xz region)
    delta_kernel<<<dim3(64, 6, 4), 256, 0, stream>>>(dbl, dwa, dwb, dba, dbb, dl_t);
    // 5) chunked scan
    scan_p1<<<dim3(6, NC, 4), 256, 0, stream>>>(u_t, dl_t, dbl, Ala, Alb, Sdl, Hloc);
    scan_p2<<<dim3(96, 4), 256, 0, stream>>>(Sdl, Hloc, Ala, Alb, h0);
    scan_p3<<<dim3(6, NC, 4), 256, 0, stream>>>(u_t, dl_t, dbl, h0, Ala, Alb, Da, Db, ya, yb);
    // 6) out_proj with fused (ya+yb)*silu(z)
    gemm_out<<<dim3(6, 32, 2), 256, 0, stream>>>(ya, yb, z_t, Wo, out);
}

// Round 6
// 752.414 us; speedup vs baseline: 2.8660x; 1.9019x over previous
//
#include <hip/hip_runtime.h>
#include <math.h>

#define BQ 2
#define LQ 4096
#define DM 768
#define DI 1536
#define DS 16
#define E80 80   // DTR + 2*DS
#define NC 32
#define CH 128   // LQ / NC

typedef _Float16 half8 __attribute__((ext_vector_type(8)));
typedef _Float16 half4v __attribute__((ext_vector_type(4)));
typedef float f32x4 __attribute__((ext_vector_type(4)));

__device__ __forceinline__ float bf2f(ushort u) { return __uint_as_float(((unsigned)u) << 16); }
__device__ __forceinline__ ushort f2bf(float x) {
    unsigned u = __float_as_uint(x);
    unsigned r = (u + 0x7fffu + ((u >> 16) & 1u)) >> 16;
    return (ushort)r;
}

// ---------------------------------------------------------------------------
// f32 -> fp16 pack (n divisible by 1024; grid = n/1024)
// ---------------------------------------------------------------------------
__global__ __launch_bounds__(256)
void pack_fp16(const float* __restrict__ src, _Float16* __restrict__ dst)
{
    long i = ((long)blockIdx.x * 256 + threadIdx.x) * 4;
    float4 v = *(const float4*)(src + i);
    half4v o = {(_Float16)v.x, (_Float16)v.y, (_Float16)v.z, (_Float16)v.w};
    *(half4v*)(dst + i) = o;
}

// ---------------------------------------------------------------------------
// MFMA NT GEMM (fp16 in, f32 out): C[m,n] = sum_k A[m,k]*B[n,k].
// 128x128 tile, BK=64. Fragment-ordered LDS (uint4): [frag 0..15][lane] x16B.
// frag f: ks = f>>3 (k-half 0/1), t = f&7 (16-row tile). Wave w stages frags
// w*4..w*4+3 of A and B; computes quadrant (mh=w&1, nh=w>>1).
// ---------------------------------------------------------------------------
__global__ __launch_bounds__(256)
void gemm_mfma(const _Float16* __restrict__ Ah, const _Float16* __restrict__ Bh,
               float* __restrict__ C, int K, int ldA, int ldB, int ldC,
               long strideA, long strideB, long strideC)
{
    __shared__ uint4 Af[16][64];
    __shared__ uint4 Bf[16][64];
    const int bz = blockIdx.z;
    const _Float16* Ab = Ah + (long)bz * strideA;
    const _Float16* Bb = Bh + (long)bz * strideB;
    float* Cb = C + (long)bz * strideC;
    const int m0 = blockIdx.y * 128, n0 = blockIdx.x * 128;
    const int tid = threadIdx.x, w = tid >> 6, lane = tid & 63;
    const int mh = w & 1, nh = w >> 1;

    const _Float16* asrc[4];
    const _Float16* bsrc[4];
#pragma unroll
    for (int i = 0; i < 4; i++) {
        int f = w * 4 + i;
        int ks = f >> 3, t = f & 7;
        asrc[i] = Ab + (long)(m0 + t * 16 + (lane & 15)) * ldA + ks * 32 + (lane >> 4) * 8;
        bsrc[i] = Bb + (long)(n0 + t * 16 + (lane & 15)) * ldB + ks * 32 + (lane >> 4) * 8;
    }

    f32x4 acc[4][4];
#pragma unroll
    for (int i = 0; i < 4; i++)
#pragma unroll
        for (int j = 0; j < 4; j++) acc[i][j] = {0.f, 0.f, 0.f, 0.f};

    for (int k0 = 0; k0 < K; k0 += 64) {
#pragma unroll
        for (int i = 0; i < 4; i++) {
            Af[w * 4 + i][lane] = *(const uint4*)asrc[i];
            Bf[w * 4 + i][lane] = *(const uint4*)bsrc[i];
            asrc[i] += 64; bsrc[i] += 64;
        }
        __syncthreads();
#pragma unroll
        for (int ks = 0; ks < 2; ks++) {
            uint4 au[4], bu[4];
#pragma unroll
            for (int i = 0; i < 4; i++) {
                au[i] = Af[ks * 8 + mh * 4 + i][lane];
                bu[i] = Bf[ks * 8 + nh * 4 + i][lane];
            }
#pragma unroll
            for (int i = 0; i < 4; i++) {
                half8 av = __builtin_bit_cast(half8, au[i]);
#pragma unroll
                for (int j = 0; j < 4; j++) {
                    half8 bv = __builtin_bit_cast(half8, bu[j]);
                    acc[i][j] = __builtin_amdgcn_mfma_f32_16x16x32_f16(
                        av, bv, acc[i][j], 0, 0, 0);
                }
            }
        }
        __syncthreads();
    }
    // epilogue: C/D layout col=lane&15, row=(lane>>4)*4+reg
    const int r0 = (lane >> 4) * 4, cn = lane & 15;
#pragma unroll
    for (int i = 0; i < 4; i++) {
        int mrow = m0 + (mh * 4 + i) * 16 + r0;
#pragma unroll
        for (int j = 0; j < 4; j++) {
            int col = n0 + (nh * 4 + j) * 16 + cn;
#pragma unroll
            for (int r = 0; r < 4; r++)
                Cb[(long)(mrow + r) * ldC + col] = acc[i][j][r];
        }
    }
}

// ---------------------------------------------------------------------------
// x_proj with fused conv+SiLU recompute; also emits u_t (bf16, [z][l][d]).
// ---------------------------------------------------------------------------
__global__ __launch_bounds__(256)
void xproj_kernel(const float* __restrict__ xz,
                  const float* __restrict__ cwa, const float* __restrict__ cba,
                  const float* __restrict__ cwb, const float* __restrict__ cbb,
                  const float* __restrict__ xpa, const float* __restrict__ xpb,
                  float* __restrict__ dbl, ushort* __restrict__ ut)
{
    __shared__ float lw[80][68];
    __shared__ float lu[32][68];
    __shared__ float lraw[64][37];
    __shared__ float lcw[64][5];
    const int l0 = blockIdx.x * 32;
    const int b = blockIdx.y, br = blockIdx.z;
    const int z = br * BQ + b;
    const float* W  = br ? xpb : xpa;
    const float* CW = br ? cwb : cwa;
    const float* CB = br ? cbb : cba;
    const float* xb = xz + (long)b * 2 * DI * LQ;
    float* out = dbl + ((long)z * LQ + l0) * E80;
    const int tid = threadIdx.x;
    const int l = tid >> 3, eg = tid & 7;
    float acc[10];
#pragma unroll
    for (int i = 0; i < 10; i++) acc[i] = 0.f;

    for (int k0 = 0; k0 < DI; k0 += 64) {
#pragma unroll
        for (int i = 0; i < 5; i++) {
            int idx = tid + i * 256;
            int e = idx >> 4, kq = (idx & 15) * 4;
            *(float4*)&lw[e][kq] = *(const float4*)&W[(long)e * DI + k0 + kq];
        }
        {
            int dd = tid >> 2, k = tid & 3;
            lcw[dd][k] = CW[(k0 + dd) * 4 + k];
            if (tid < 64) lcw[tid][4] = CB[k0 + tid];
        }
        for (int i = tid; i < 64 * 35; i += 256) {
            int dd = i / 35, cc = i % 35;
            int src = l0 - 3 + cc;
            float v = 0.f;
            if (src >= 0 && src < LQ)
                v = xb[(long)(k0 + dd) * LQ + (br ? (LQ - 1 - src) : src)];
            lraw[dd][cc] = v;
        }
        __syncthreads();
#pragma unroll
        for (int q = 0; q < 8; q++) {
            int o = tid + q * 256;
            int dd = o & 63, ll = o >> 6;
            float a = lcw[dd][4];
            a = fmaf(lraw[dd][ll + 0], lcw[dd][0], a);
            a = fmaf(lraw[dd][ll + 1], lcw[dd][1], a);
            a = fmaf(lraw[dd][ll + 2], lcw[dd][2], a);
            a = fmaf(lraw[dd][ll + 3], lcw[dd][3], a);
            float uu = a * (1.f / (1.f + __expf(-a)));
            lu[ll][dd] = uu;
            ut[((long)z * LQ + l0 + ll) * DI + k0 + dd] = f2bf(uu);
        }
        __syncthreads();
#pragma unroll
        for (int kk = 0; kk < 64; kk += 4) {
            float4 uv = *(const float4*)&lu[l][kk];
#pragma unroll
            for (int i = 0; i < 10; i++) {
                float4 wv = *(const float4*)&lw[eg * 10 + i][kk];
                acc[i] = fmaf(uv.x, wv.x, fmaf(uv.y, wv.y,
                         fmaf(uv.z, wv.z, fmaf(uv.w, wv.w, acc[i]))));
            }
        }
        __syncthreads();
    }
#pragma unroll
    for (int i = 0; i < 10; i++) out[(long)l * E80 + eg * 10 + i] = acc[i];
}

// ---------------------------------------------------------------------------
// Transpose z-half of xz [b][DI..2DI][l] -> z_t bf16 [b][l][d].
// ---------------------------------------------------------------------------
__global__ __launch_bounds__(256)
void transpose_z(const float* __restrict__ xz, ushort* __restrict__ zt)
{
    __shared__ float t[64][65];
    const int l0 = blockIdx.x * 64, d0 = blockIdx.y * 64, b = blockIdx.z;
    const float* src = xz + ((long)b * 2 * DI + DI + d0) * LQ + l0;
    const int tid = threadIdx.x;
    const int r = tid >> 4, c4 = (tid & 15) * 4;
#pragma unroll
    for (int i = 0; i < 4; i++) {
        float4 v = *(const float4*)&src[(long)(r + i * 16) * LQ + c4];
        t[c4 + 0][r + i * 16] = v.x; t[c4 + 1][r + i * 16] = v.y;
        t[c4 + 2][r + i * 16] = v.z; t[c4 + 3][r + i * 16] = v.w;
    }
    __syncthreads();
    const int l = tid >> 2, seg = (tid & 3) * 16;
    ushort tmp[16];
#pragma unroll
    for (int j = 0; j < 16; j++) tmp[j] = f2bf(t[l][seg + j]);
    uint4 p0, p1;
    p0.x = tmp[0] | (tmp[1] << 16);  p0.y = tmp[2] | (tmp[3] << 16);
    p0.z = tmp[4] | (tmp[5] << 16);  p0.w = tmp[6] | (tmp[7] << 16);
    p1.x = tmp[8] | (tmp[9] << 16);  p1.y = tmp[10] | (tmp[11] << 16);
    p1.z = tmp[12] | (tmp[13] << 16); p1.w = tmp[14] | (tmp[15] << 16);
    ushort* dst = zt + ((long)b * LQ + l0 + l) * DI + d0 + seg;
    *(uint4*)dst = p0;
    *(uint4*)(dst + 8) = p1;
}

// ---------------------------------------------------------------------------
// delta GEMM: dl_t[z][t][d] = softplus(dot48(dbl[z][t][0:48], W[d]) + bias[d])
// ---------------------------------------------------------------------------
__global__ __launch_bounds__(256)
void delta_kernel(const float* __restrict__ dbl,
                  const float* __restrict__ dwa, const float* __restrict__ dwb,
                  const float* __restrict__ dba, const float* __restrict__ dbb,
                  ushort* __restrict__ dlt)
{
    __shared__ float sdt[64][49];
    const int t0 = blockIdx.x * 64;
    const int d = blockIdx.y * 256 + threadIdx.x;
    const int z = blockIdx.z;
    const float* W    = (z >> 1) ? dwb : dwa;
    const float* bias = (z >> 1) ? dbb : dba;
    const float* dblb = dbl + (long)z * LQ * E80;

    float w[48];
#pragma unroll
    for (int i = 0; i < 12; i++) {
        float4 v = *(const float4*)&W[(long)d * 48 + i * 4];
        w[i * 4] = v.x; w[i * 4 + 1] = v.y; w[i * 4 + 2] = v.z; w[i * 4 + 3] = v.w;
    }
    const float bi = bias[d];
    for (int f = threadIdx.x; f < 768; f += 256) {
        int t = f / 12, q = f % 12;
        float4 v = *(const float4*)&dblb[(long)(t0 + t) * E80 + q * 4];
        sdt[t][q * 4 + 0] = v.x; sdt[t][q * 4 + 1] = v.y;
        sdt[t][q * 4 + 2] = v.z; sdt[t][q * 4 + 3] = v.w;
    }
    __syncthreads();
    for (int t = 0; t < 64; t++) {
        float a = bi;
#pragma unroll
        for (int k = 0; k < 48; k++) a = fmaf(sdt[t][k], w[k], a);
        float sp = (a > 20.f) ? a : log1pf(__expf(a));
        dlt[((long)z * LQ + t0 + t) * DI + d] = f2bf(sp);
    }
}

// ---------------------------------------------------------------------------
// Scan pass 1: per-chunk summaries (lane = channel, 16 states in VGPRs).
// ---------------------------------------------------------------------------
__global__ __launch_bounds__(256)
void scan_p1(const ushort* __restrict__ ut, const ushort* __restrict__ dlt,
             const float* __restrict__ dbl,
             const float* __restrict__ Ala, const float* __restrict__ Alb,
             float* __restrict__ Sdl, float* __restrict__ Hloc)
{
    const int d = blockIdx.x * 256 + threadIdx.x;
    const int c = blockIdx.y;
    const int z = blockIdx.z;
    const int br = z >> 1;
    const float* Al = br ? Alb : Ala;
    float An[16];
#pragma unroll
    for (int i = 0; i < 4; i++) {
        float4 v = *(const float4*)&Al[(long)d * 16 + i * 4];
        An[i * 4] = -__expf(v.x); An[i * 4 + 1] = -__expf(v.y);
        An[i * 4 + 2] = -__expf(v.z); An[i * 4 + 3] = -__expf(v.w);
    }
    const long lbase = (long)z * LQ + (long)c * CH;
    const ushort* ub = ut + lbase * DI + d;
    const ushort* db = dlt + lbase * DI + d;
    const float* bc = dbl + lbase * E80 + 48;

    float h[16];
#pragma unroll
    for (int n = 0; n < 16; n++) h[n] = 0.f;
    float sdl = 0.f;

    for (int t0 = 0; t0 < CH; t0 += 8) {
        ushort uu[8], dd[8];
#pragma unroll
        for (int j = 0; j < 8; j++) {
            uu[j] = ub[(long)(t0 + j) * DI];
            dd[j] = db[(long)(t0 + j) * DI];
        }
#pragma unroll
        for (int j = 0; j < 8; j++) {
            float dl = bf2f(dd[j]);
            float u  = bf2f(uu[j]);
            sdl += dl;
            float du = dl * u;
            const float* Bp = bc + (long)(t0 + j) * E80;
            float Bv[16];
#pragma unroll
            for (int i = 0; i < 4; i++) {
                float4 v = *(const float4*)&Bp[i * 4];
                Bv[i * 4] = v.x; Bv[i * 4 + 1] = v.y;
                Bv[i * 4 + 2] = v.z; Bv[i * 4 + 3] = v.w;
            }
#pragma unroll
            for (int n = 0; n < 16; n++)
                h[n] = fmaf(__expf(dl * An[n]), h[n], du * Bv[n]);
        }
    }
    Sdl[((long)z * NC + c) * DI + d] = sdl;
    float* Hp = Hloc + (((long)z * NC + c) * DI + d) * 16;
#pragma unroll
    for (int i = 0; i < 4; i++)
        *(float4*)&Hp[i * 4] = make_float4(h[i * 4], h[i * 4 + 1], h[i * 4 + 2], h[i * 4 + 3]);
}

// ---------------------------------------------------------------------------
// Scan pass 2: inter-chunk scan.
// ---------------------------------------------------------------------------
__global__ __launch_bounds__(256)
void scan_p2(const float* __restrict__ Sdl, const float* __restrict__ Hloc,
             const float* __restrict__ Ala, const float* __restrict__ Alb,
             float* __restrict__ h0)
{
    const int idx = blockIdx.x * 256 + threadIdx.x;
    const int z = blockIdx.y;
    const int d = idx >> 4, n = idx & 15;
    const float* Al = (z >> 1) ? Alb : Ala;
    const float An = -__expf(Al[(long)d * 16 + n]);
    float h = 0.f;
    for (int c = 0; c < NC; c++) {
        h0[((long)z * NC + c) * DI * 16 + idx] = h;
        float sdl = Sdl[((long)z * NC + c) * DI + d];
        float Hl = Hloc[((long)z * NC + c) * DI * 16 + idx];
        h = fmaf(__expf(An * sdl), h, Hl);
    }
}

// ---------------------------------------------------------------------------
// Scan pass 3: re-run chunks from h0, emit y (+D) bf16 [l][d], B pre-flipped.
// ---------------------------------------------------------------------------
__global__ __launch_bounds__(256)
void scan_p3(const ushort* __restrict__ ut, const ushort* __restrict__ dlt,
             const float* __restrict__ dbl, const float* __restrict__ h0,
             const float* __restrict__ Ala, const float* __restrict__ Alb,
             const float* __restrict__ Da, const float* __restrict__ Db,
             ushort* __restrict__ ya, ushort* __restrict__ yb)
{
    const int d = blockIdx.x * 256 + threadIdx.x;
    const int c = blockIdx.y;
    const int z = blockIdx.z;
    const int br = z >> 1, b = z & 1;
    const float* Al = br ? Alb : Ala;
    float An[16];
#pragma unroll
    for (int i = 0; i < 4; i++) {
        float4 v = *(const float4*)&Al[(long)d * 16 + i * 4];
        An[i * 4] = -__expf(v.x); An[i * 4 + 1] = -__expf(v.y);
        An[i * 4 + 2] = -__expf(v.z); An[i * 4 + 3] = -__expf(v.w);
    }
    const float Dd = (br ? Db : Da)[d];
    const long lbase = (long)z * LQ + (long)c * CH;
    const ushort* ub = ut + lbase * DI + d;
    const ushort* db = dlt + lbase * DI + d;
    const float* bc = dbl + lbase * E80 + 48;
    const float* Hp = h0 + (((long)z * NC + c) * DI + d) * 16;
    float h[16];
#pragma unroll
    for (int i = 0; i < 4; i++) {
        float4 v = *(const float4*)&Hp[i * 4];
        h[i * 4] = v.x; h[i * 4 + 1] = v.y; h[i * 4 + 2] = v.z; h[i * 4 + 3] = v.w;
    }
    ushort* yo = br ? yb : ya;

    for (int t0 = 0; t0 < CH; t0 += 8) {
        ushort uu[8], dd[8];
#pragma unroll
        for (int j = 0; j < 8; j++) {
            uu[j] = ub[(long)(t0 + j) * DI];
            dd[j] = db[(long)(t0 + j) * DI];
        }
#pragma unroll
        for (int j = 0; j < 8; j++) {
            float dl = bf2f(dd[j]);
            float u  = bf2f(uu[j]);
            float du = dl * u;
            const float* Bp = bc + (long)(t0 + j) * E80;
            float Bv[16], Cv[16];
#pragma unroll
            for (int i = 0; i < 4; i++) {
                float4 v = *(const float4*)&Bp[i * 4];
                Bv[i * 4] = v.x; Bv[i * 4 + 1] = v.y;
                Bv[i * 4 + 2] = v.z; Bv[i * 4 + 3] = v.w;
                float4 w2 = *(const float4*)&Bp[16 + i * 4];
                Cv[i * 4] = w2.x; Cv[i * 4 + 1] = w2.y;
                Cv[i * 4 + 2] = w2.z; Cv[i * 4 + 3] = w2.w;
            }
            float y = u * Dd;
#pragma unroll
            for (int n = 0; n < 16; n++) {
                h[n] = fmaf(__expf(dl * An[n]), h[n], du * Bv[n]);
                y = fmaf(h[n], Cv[n], y);
            }
            int t = c * CH + t0 + j;
            long lorig = br ? (LQ - 1 - t) : t;
            yo[((long)b * LQ + lorig) * DI + d] = f2bf(y);
        }
    }
}

// ---------------------------------------------------------------------------
// yf = (ya + yb) * silu(z)  -> fp16 [b][l][d]. 8 elements/thread.
// ---------------------------------------------------------------------------
__global__ __launch_bounds__(256)
void fuse_y(const ushort* __restrict__ ya, const ushort* __restrict__ yb,
            const ushort* __restrict__ zt, _Float16* __restrict__ yf)
{
    long i = ((long)blockIdx.x * 256 + threadIdx.x) * 8;
    uint4 pa = *(const uint4*)(ya + i);
    uint4 pb = *(const uint4*)(yb + i);
    uint4 pz = *(const uint4*)(zt + i);
    unsigned wa[4] = {pa.x, pa.y, pa.z, pa.w};
    unsigned wb[4] = {pb.x, pb.y, pb.z, pb.w};
    unsigned wz[4] = {pz.x, pz.y, pz.z, pz.w};
    half8 o;
#pragma unroll
    for (int q = 0; q < 4; q++) {
        float y0 = __uint_as_float(wa[q] << 16) + __uint_as_float(wb[q] << 16);
        float y1 = __uint_as_float(wa[q] & 0xffff0000u) + __uint_as_float(wb[q] & 0xffff0000u);
        float z0 = __uint_as_float(wz[q] << 16);
        float z1 = __uint_as_float(wz[q] & 0xffff0000u);
        o[q * 2 + 0] = (_Float16)(y0 * (z0 / (1.f + __expf(-z0))));
        o[q * 2 + 1] = (_Float16)(y1 * (z1 / (1.f + __expf(-z1))));
    }
    *(half8*)(yf + i) = o;
}

// ---------------------------------------------------------------------------
extern "C" void kernel_launch(void* const* d_in, const int* in_sizes, int n_in,
                              void* d_out, int out_size, void* d_ws, size_t ws_size,
                              hipStream_t stream)
{
    const float* hs  = (const float*)d_in[0];
    const float* Wi  = (const float*)d_in[1];
    const float* Wo  = (const float*)d_in[2];
    const float* cwa = (const float*)d_in[3];
    const float* cba = (const float*)d_in[4];
    const float* cwb = (const float*)d_in[5];
    const float* cbb = (const float*)d_in[6];
    const float* xpa = (const float*)d_in[7];
    const float* xpb = (const float*)d_in[8];
    const float* dwa = (const float*)d_in[9];
    const float* dwb = (const float*)d_in[10];
    const float* dba = (const float*)d_in[11];
    const float* dbb = (const float*)d_in[12];
    const float* Ala = (const float*)d_in[13];
    const float* Alb = (const float*)d_in[14];
    const float* Da  = (const float*)d_in[15];
    const float* Db  = (const float*)d_in[16];
    float* out = (float*)d_out;

    float* ws = (float*)d_ws;
    // Region A (xz) is reused for dl_t/ya/yb after transpose_z.
    float*    xz   = ws;                                // [0 .. 25165824)
    ushort*   dl_t = (ushort*)ws;
    ushort*   ya   = (ushort*)(ws + 12582912);
    ushort*   yb   = (ushort*)(ws + 18874368);
    float*    dbl  = ws + 25165824;                     // [.. 26476544)
    ushort*   u_t  = (ushort*)(ws + 26476544);          // [.. 39059456)
    _Float16* yf   = (_Float16*)(ws + 26476544);        // aliases u_t (dead after p3)
    ushort*   z_t  = (ushort*)(ws + 39059456);          // [.. 45350912)
    float*    Sdl  = ws + 45350912;                     // [.. 45547520)
    float*    Hloc = ws + 45547520;                     // [.. 48693248)
    float*    h0   = ws + 48693248;                     // [.. 51838976)
    _Float16* hsb  = (_Float16*)(ws + 45350912);        // aliases Sdl/Hloc (dead before scan)
    _Float16* Wib  = (_Float16*)(ws + 48496640);        // aliases Hloc/h0 tail (dead before scan)
    _Float16* Wob  = (_Float16*)(ws + 45350912);        // aliases Sdl/Hloc (packed AFTER scan_p3)
    // peak footprint: 51,838,976 floats = 207.36 MB (== R3's passing layout)

    // 0) fp16 packs for in_proj
    pack_fp16<<<6144, 256, 0, stream>>>(hs, hsb);   // 2*4096*768
    pack_fp16<<<2304, 256, 0, stream>>>(Wi, Wib);   // 3072*768
    // 1) in_proj (MFMA): xz[b,e,l] = sum_d Wi[e,d]*hs[b,l,d]
    gemm_mfma<<<dim3(32, 24, 2), 256, 0, stream>>>(
        Wib, hsb, xz, DM, DM, DM, LQ,
        0L, (long)LQ * DM, (long)2 * DI * LQ);
    // 2) x_proj (+ u_t bf16 emit)
    xproj_kernel<<<dim3(128, 2, 2), 256, 0, stream>>>(
        xz, cwa, cba, cwb, cbb, xpa, xpb, dbl, u_t);
    // 3) z transpose to bf16 [l][d]   (last reader of xz)
    transpose_z<<<dim3(64, 24, 2), 256, 0, stream>>>(xz, z_t);
    // 4) delta (bf16 [t][d]; overwrites xz region)
    delta_kernel<<<dim3(64, 6, 4), 256, 0, stream>>>(dbl, dwa, dwb, dba, dbb, dl_t);
    // 5) chunked scan
    scan_p1<<<dim3(6, NC, 4), 256, 0, stream>>>(u_t, dl_t, dbl, Ala, Alb, Sdl, Hloc);
    scan_p2<<<dim3(96, 4), 256, 0, stream>>>(Sdl, Hloc, Ala, Alb, h0);
    scan_p3<<<dim3(6, NC, 4), 256, 0, stream>>>(u_t, dl_t, dbl, h0, Ala, Alb, Da, Db, ya, yb);
    // 6) pack Wo now that Sdl/Hloc are dead; fuse (ya+yb)*silu(z) -> yf (fp16)
    pack_fp16<<<1152, 256, 0, stream>>>(Wo, Wob);   // 768*1536
    fuse_y<<<6144, 256, 0, stream>>>(ya, yb, z_t, yf);
    // 7) out_proj (MFMA): out[b,l,o] = sum_d yf[b,l,d]*Wo[o,d]
    gemm_mfma<<<dim3(6, 32, 2), 256, 0, stream>>>(
        yf, Wob, out, DI, DI, DI, DM,
        (long)LQ * DI, 0L, (long)LQ * DM);
}

// Round 8
// 657.726 us; speedup vs baseline: 3.2786x; 1.1440x over previous
//
#include <hip/hip_runtime.h>
#include <math.h>

#define BQ 2
#define LQ 4096
#define DM 768
#define DI 1536
#define DS 16
#define E80 80   // DTR + 2*DS
#define NC 32
#define CH 128   // LQ / NC

typedef _Float16 half8 __attribute__((ext_vector_type(8)));
typedef _Float16 half4v __attribute__((ext_vector_type(4)));
typedef float f32x4 __attribute__((ext_vector_type(4)));

__device__ __forceinline__ ushort f2h_bits(float x) {
    return __builtin_bit_cast(ushort, (_Float16)x);
}

// ---------------------------------------------------------------------------
// f32 -> fp16 pack (n divisible by 1024; grid = n/1024)
// ---------------------------------------------------------------------------
__global__ __launch_bounds__(256)
void pack_fp16(const float* __restrict__ src, _Float16* __restrict__ dst)
{
    long i = ((long)blockIdx.x * 256 + threadIdx.x) * 4;
    float4 v = *(const float4*)(src + i);
    half4v o = {(_Float16)v.x, (_Float16)v.y, (_Float16)v.z, (_Float16)v.w};
    *(half4v*)(dst + i) = o;
}

// ---------------------------------------------------------------------------
// MFMA NT GEMM (fp16 in, f32 out): C[m,n] = sum_k A[m,k]*B[n,k].
// 128x128 tile, BK=64. Fragment-ordered LDS (uint4): [frag][lane] x16B.
// NOTE: all __shared__ arrays in this file are 32-bit+ types ON PURPOSE —
// 16-bit-typed shared arrays correlate 6/6 with container-killing faults
// (R4/R5/R7 died, R2/R3/R6 passed).
// ---------------------------------------------------------------------------
__global__ __launch_bounds__(256)
void gemm_mfma(const _Float16* __restrict__ Ah, const _Float16* __restrict__ Bh,
               float* __restrict__ C, int K, int ldA, int ldB, int ldC,
               long strideA, long strideB, long strideC)
{
    __shared__ uint4 Af[16][64];
    __shared__ uint4 Bf[16][64];
    const int bz = blockIdx.z;
    const _Float16* Ab = Ah + (long)bz * strideA;
    const _Float16* Bb = Bh + (long)bz * strideB;
    float* Cb = C + (long)bz * strideC;
    const int m0 = blockIdx.y * 128, n0 = blockIdx.x * 128;
    const int tid = threadIdx.x, w = tid >> 6, lane = tid & 63;
    const int mh = w & 1, nh = w >> 1;

    const _Float16* asrc[4];
    const _Float16* bsrc[4];
#pragma unroll
    for (int i = 0; i < 4; i++) {
        int f = w * 4 + i;
        int ks = f >> 3, t = f & 7;
        asrc[i] = Ab + (long)(m0 + t * 16 + (lane & 15)) * ldA + ks * 32 + (lane >> 4) * 8;
        bsrc[i] = Bb + (long)(n0 + t * 16 + (lane & 15)) * ldB + ks * 32 + (lane >> 4) * 8;
    }

    f32x4 acc[4][4];
#pragma unroll
    for (int i = 0; i < 4; i++)
#pragma unroll
        for (int j = 0; j < 4; j++) acc[i][j] = {0.f, 0.f, 0.f, 0.f};

    for (int k0 = 0; k0 < K; k0 += 64) {
#pragma unroll
        for (int i = 0; i < 4; i++) {
            Af[w * 4 + i][lane] = *(const uint4*)asrc[i];
            Bf[w * 4 + i][lane] = *(const uint4*)bsrc[i];
            asrc[i] += 64; bsrc[i] += 64;
        }
        __syncthreads();
#pragma unroll
        for (int ks = 0; ks < 2; ks++) {
            uint4 au[4], bu[4];
#pragma unroll
            for (int i = 0; i < 4; i++) {
                au[i] = Af[ks * 8 + mh * 4 + i][lane];
                bu[i] = Bf[ks * 8 + nh * 4 + i][lane];
            }
#pragma unroll
            for (int i = 0; i < 4; i++) {
                half8 av = __builtin_bit_cast(half8, au[i]);
#pragma unroll
                for (int j = 0; j < 4; j++) {
                    half8 bv = __builtin_bit_cast(half8, bu[j]);
                    acc[i][j] = __builtin_amdgcn_mfma_f32_16x16x32_f16(
                        av, bv, acc[i][j], 0, 0, 0);
                }
            }
        }
        __syncthreads();
    }
    const int r0 = (lane >> 4) * 4, cn = lane & 15;
#pragma unroll
    for (int i = 0; i < 4; i++) {
        int mrow = m0 + (mh * 4 + i) * 16 + r0;
#pragma unroll
        for (int j = 0; j < 4; j++) {
            int col = n0 + (nh * 4 + j) * 16 + cn;
#pragma unroll
            for (int r = 0; r < 4; r++)
                Cb[(long)(mrow + r) * ldC + col] = acc[i][j][r];
        }
    }
}

// ---------------------------------------------------------------------------
// Depthwise conv(k=4)+SiLU with transpose: xz x-half [b][d][l] fp32 ->
// u_t fp16 [z][l][d]. br=1 consumes reversed sequence.
// Tile: 64 d x 64 l. Grid (LQ/64, DI/64, 4).
// cu is FLOAT in LDS (see note in gemm_mfma); fp16 conversion at store.
// ---------------------------------------------------------------------------
__global__ __launch_bounds__(256)
void conv_silu_t(const float* __restrict__ xz,
                 const float* __restrict__ cwa, const float* __restrict__ cba,
                 const float* __restrict__ cwb, const float* __restrict__ cbb,
                 _Float16* __restrict__ ut)
{
    __shared__ float lraw[64][67];     // [d][l0-3 .. l0+63]
    __shared__ float cu[64][72];       // [l][d] fp32, row stride 288 B (16-B mult)
    __shared__ float lcw[64][5];
    const int l0 = blockIdx.x * 64, d0 = blockIdx.y * 64;
    const int z = blockIdx.z;
    const int br = z >> 1, b = z & 1;
    const float* xb = xz + ((long)b * 2 * DI + d0) * LQ;
    const float* CW = br ? cwb : cwa;
    const float* CB = br ? cbb : cba;
    const int tid = threadIdx.x;

    {   // conv weights + bias
        int dd = tid >> 2, k = tid & 3;
        lcw[dd][k] = CW[(d0 + dd) * 4 + k];
        if (tid < 64) lcw[tid][4] = CB[d0 + tid];
    }
    // stage raw x (reversed for br=1)
    for (int i = tid; i < 64 * 67; i += 256) {
        int dd = i / 67, cc = i % 67;
        int src = l0 - 3 + cc;
        float v = 0.f;
        if (src >= 0)
            v = xb[(long)dd * LQ + (br ? (LQ - 1 - src) : src)];
        lraw[dd][cc] = v;
    }
    __syncthreads();
    // conv + silu -> cu[l][d] (fp32)
#pragma unroll
    for (int q = 0; q < 16; q++) {
        int o = tid + q * 256;
        int dd = o & 63, ll = o >> 6;
        float a = lcw[dd][4];
        a = fmaf(lraw[dd][ll + 0], lcw[dd][0], a);
        a = fmaf(lraw[dd][ll + 1], lcw[dd][1], a);
        a = fmaf(lraw[dd][ll + 2], lcw[dd][2], a);
        a = fmaf(lraw[dd][ll + 3], lcw[dd][3], a);
        cu[ll][dd] = a * (1.f / (1.f + __expf(-a)));
    }
    __syncthreads();
    // store: 8 halves per thread, 2 passes; convert fp32->fp16 here
    const int dg = (tid & 7) * 8;
#pragma unroll
    for (int p = 0; p < 2; p++) {
        int ll = (tid >> 3) + p * 32;
        float4 v0 = *(const float4*)&cu[ll][dg];
        float4 v1 = *(const float4*)&cu[ll][dg + 4];
        uint4 o;
        o.x = f2h_bits(v0.x) | ((unsigned)f2h_bits(v0.y) << 16);
        o.y = f2h_bits(v0.z) | ((unsigned)f2h_bits(v0.w) << 16);
        o.z = f2h_bits(v1.x) | ((unsigned)f2h_bits(v1.y) << 16);
        o.w = f2h_bits(v1.z) | ((unsigned)f2h_bits(v1.w) << 16);
        *(uint4*)(ut + ((long)z * LQ + l0 + ll) * DI + d0 + dg) = o;
    }
}

// ---------------------------------------------------------------------------
// x_proj MFMA GEMM: dbl[z][l][e] = sum_d u_t[z][l][d] * xpw[br][e][d].
// M-tile 64, N=80 (5x16), BK=64. Grid (LQ/64, 4).
// ---------------------------------------------------------------------------
__global__ __launch_bounds__(256)
void xproj_mfma(const _Float16* __restrict__ ut, const _Float16* __restrict__ xpw,
                float* __restrict__ dbl)
{
    __shared__ uint4 Af[8][64];    // f = ks*4 + row-tile
    __shared__ uint4 Bf[10][64];   // f = col-tile*2 + ks
    const int m0 = blockIdx.x * 64;
    const int z = blockIdx.y;
    const _Float16* A = ut + (long)z * LQ * DI;
    const _Float16* W = xpw + (long)(z >> 1) * E80 * DI;
    float* out = dbl + (long)z * LQ * E80;
    const int tid = threadIdx.x, w = tid >> 6, lane = tid & 63;

    f32x4 acc[5];
#pragma unroll
    for (int j = 0; j < 5; j++) acc[j] = {0.f, 0.f, 0.f, 0.f};

    for (int k0 = 0; k0 < DI; k0 += 64) {
#pragma unroll
        for (int i = 0; i < 2; i++) {
            int f = w + i * 4;
            int row = m0 + (f & 3) * 16 + (lane & 15);
            int koff = k0 + (f >> 2) * 32 + (lane >> 4) * 8;
            Af[f][lane] = *(const uint4*)(A + (long)row * DI + koff);
        }
        for (int i = tid; i < 640; i += 256) {
            int f = i >> 6, ln = i & 63;
            int e = (f >> 1) * 16 + (ln & 15);
            int koff = k0 + (f & 1) * 32 + (ln >> 4) * 8;
            Bf[f][ln] = *(const uint4*)(W + (long)e * DI + koff);
        }
        __syncthreads();
#pragma unroll
        for (int ks = 0; ks < 2; ks++) {
            half8 av = __builtin_bit_cast(half8, Af[ks * 4 + w][lane]);
#pragma unroll
            for (int j = 0; j < 5; j++) {
                half8 bv = __builtin_bit_cast(half8, Bf[j * 2 + ks][lane]);
                acc[j] = __builtin_amdgcn_mfma_f32_16x16x32_f16(av, bv, acc[j], 0, 0, 0);
            }
        }
        __syncthreads();
    }
    const int r0 = (lane >> 4) * 4, cn = lane & 15;
    const int row = m0 + w * 16 + r0;
#pragma unroll
    for (int j = 0; j < 5; j++)
#pragma unroll
        for (int r = 0; r < 4; r++)
            out[(long)(row + r) * E80 + j * 16 + cn] = acc[j][r];
}

// ---------------------------------------------------------------------------
// Transpose z-half of xz [b][DI..2DI][l] -> z_t fp16 [b][l][d].
// ---------------------------------------------------------------------------
__global__ __launch_bounds__(256)
void transpose_z(const float* __restrict__ xz, _Float16* __restrict__ zt)
{
    __shared__ float t[64][65];
    const int l0 = blockIdx.x * 64, d0 = blockIdx.y * 64, b = blockIdx.z;
    const float* src = xz + ((long)b * 2 * DI + DI + d0) * LQ + l0;
    const int tid = threadIdx.x;
    const int r = tid >> 4, c4 = (tid & 15) * 4;
#pragma unroll
    for (int i = 0; i < 4; i++) {
        float4 v = *(const float4*)&src[(long)(r + i * 16) * LQ + c4];
        t[c4 + 0][r + i * 16] = v.x; t[c4 + 1][r + i * 16] = v.y;
        t[c4 + 2][r + i * 16] = v.z; t[c4 + 3][r + i * 16] = v.w;
    }
    __syncthreads();
    const int l = tid >> 2, seg = (tid & 3) * 16;
    ushort tmp[16];
#pragma unroll
    for (int j = 0; j < 16; j++) tmp[j] = f2h_bits(t[l][seg + j]);
    uint4 p0, p1;
    p0.x = tmp[0] | (tmp[1] << 16);  p0.y = tmp[2] | (tmp[3] << 16);
    p0.z = tmp[4] | (tmp[5] << 16);  p0.w = tmp[6] | (tmp[7] << 16);
    p1.x = tmp[8] | (tmp[9] << 16);  p1.y = tmp[10] | (tmp[11] << 16);
    p1.z = tmp[12] | (tmp[13] << 16); p1.w = tmp[14] | (tmp[15] << 16);
    ushort* dst = (ushort*)(zt + ((long)b * LQ + l0 + l) * DI + d0 + seg);
    *(uint4*)dst = p0;
    *(uint4*)(dst + 8) = p1;
}

// ---------------------------------------------------------------------------
// delta GEMM: dl_t[z][t][d] = softplus(dot48(dbl[z][t][0:48], W[d]) + bias[d])
// ---------------------------------------------------------------------------
__global__ __launch_bounds__(256)
void delta_kernel(const float* __restrict__ dbl,
                  const float* __restrict__ dwa, const float* __restrict__ dwb,
                  const float* __restrict__ dba, const float* __restrict__ dbb,
                  _Float16* __restrict__ dlt)
{
    __shared__ float sdt[64][49];
    const int t0 = blockIdx.x * 64;
    const int d = blockIdx.y * 256 + threadIdx.x;
    const int z = blockIdx.z;
    const float* W    = (z >> 1) ? dwb : dwa;
    const float* bias = (z >> 1) ? dbb : dba;
    const float* dblb = dbl + (long)z * LQ * E80;

    float w[48];
#pragma unroll
    for (int i = 0; i < 12; i++) {
        float4 v = *(const float4*)&W[(long)d * 48 + i * 4];
        w[i * 4] = v.x; w[i * 4 + 1] = v.y; w[i * 4 + 2] = v.z; w[i * 4 + 3] = v.w;
    }
    const float bi = bias[d];
    for (int f = threadIdx.x; f < 768; f += 256) {
        int t = f / 12, q = f % 12;
        float4 v = *(const float4*)&dblb[(long)(t0 + t) * E80 + q * 4];
        sdt[t][q * 4 + 0] = v.x; sdt[t][q * 4 + 1] = v.y;
        sdt[t][q * 4 + 2] = v.z; sdt[t][q * 4 + 3] = v.w;
    }
    __syncthreads();
    for (int t = 0; t < 64; t++) {
        float a = bi;
#pragma unroll
        for (int k = 0; k < 48; k++) a = fmaf(sdt[t][k], w[k], a);
        float sp = (a > 20.f) ? a : log1pf(__expf(a));
        dlt[((long)z * LQ + t0 + t) * DI + d] = (_Float16)sp;
    }
}

// ---------------------------------------------------------------------------
// Scan pass 1: per-chunk summaries (lane = channel, 16 states in VGPRs).
// ---------------------------------------------------------------------------
__global__ __launch_bounds__(256)
void scan_p1(const _Float16* __restrict__ ut, const _Float16* __restrict__ dlt,
             const float* __restrict__ dbl,
             const float* __restrict__ Ala, const float* __restrict__ Alb,
             float* __restrict__ Sdl, float* __restrict__ Hloc)
{
    const int d = blockIdx.x * 256 + threadIdx.x;
    const int c = blockIdx.y;
    const int z = blockIdx.z;
    const int br = z >> 1;
    const float* Al = br ? Alb : Ala;
    float An[16];
#pragma unroll
    for (int i = 0; i < 4; i++) {
        float4 v = *(const float4*)&Al[(long)d * 16 + i * 4];
        An[i * 4] = -__expf(v.x); An[i * 4 + 1] = -__expf(v.y);
        An[i * 4 + 2] = -__expf(v.z); An[i * 4 + 3] = -__expf(v.w);
    }
    const long lbase = (long)z * LQ + (long)c * CH;
    const _Float16* ub = ut + lbase * DI + d;
    const _Float16* db = dlt + lbase * DI + d;
    const float* bc = dbl + lbase * E80 + 48;

    float h[16];
#pragma unroll
    for (int n = 0; n < 16; n++) h[n] = 0.f;
    float sdl = 0.f;

    for (int t0 = 0; t0 < CH; t0 += 8) {
        _Float16 uu[8], dd[8];
#pragma unroll
        for (int j = 0; j < 8; j++) {
            uu[j] = ub[(long)(t0 + j) * DI];
            dd[j] = db[(long)(t0 + j) * DI];
        }
#pragma unroll
        for (int j = 0; j < 8; j++) {
            float dl = (float)dd[j];
            float u  = (float)uu[j];
            sdl += dl;
            float du = dl * u;
            const float* Bp = bc + (long)(t0 + j) * E80;
            float Bv[16];
#pragma unroll
            for (int i = 0; i < 4; i++) {
                float4 v = *(const float4*)&Bp[i * 4];
                Bv[i * 4] = v.x; Bv[i * 4 + 1] = v.y;
                Bv[i * 4 + 2] = v.z; Bv[i * 4 + 3] = v.w;
            }
#pragma unroll
            for (int n = 0; n < 16; n++)
                h[n] = fmaf(__expf(dl * An[n]), h[n], du * Bv[n]);
        }
    }
    Sdl[((long)z * NC + c) * DI + d] = sdl;
    float* Hp = Hloc + (((long)z * NC + c) * DI + d) * 16;
#pragma unroll
    for (int i = 0; i < 4; i++)
        *(float4*)&Hp[i * 4] = make_float4(h[i * 4], h[i * 4 + 1], h[i * 4 + 2], h[i * 4 + 3]);
}

// ---------------------------------------------------------------------------
// Scan pass 2: inter-chunk scan.
// ---------------------------------------------------------------------------
__global__ __launch_bounds__(256)
void scan_p2(const float* __restrict__ Sdl, const float* __restrict__ Hloc,
             const float* __restrict__ Ala, const float* __restrict__ Alb,
             float* __restrict__ h0)
{
    const int idx = blockIdx.x * 256 + threadIdx.x;
    const int z = blockIdx.y;
    const int d = idx >> 4, n = idx & 15;
    const float* Al = (z >> 1) ? Alb : Ala;
    const float An = -__expf(Al[(long)d * 16 + n]);
    float h = 0.f;
    for (int c = 0; c < NC; c++) {
        h0[((long)z * NC + c) * DI * 16 + idx] = h;
        float sdl = Sdl[((long)z * NC + c) * DI + d];
        float Hl = Hloc[((long)z * NC + c) * DI * 16 + idx];
        h = fmaf(__expf(An * sdl), h, Hl);
    }
}

// ---------------------------------------------------------------------------
// Scan pass 3: re-run chunks from h0, emit y (+D) fp16 [l][d], B pre-flipped.
// ---------------------------------------------------------------------------
__global__ __launch_bounds__(256)
void scan_p3(const _Float16* __restrict__ ut, const _Float16* __restrict__ dlt,
             const float* __restrict__ dbl, const float* __restrict__ h0,
             const float* __restrict__ Ala, const float* __restrict__ Alb,
             const float* __restrict__ Da, const float* __restrict__ Db,
             _Float16* __restrict__ ya, _Float16* __restrict__ yb)
{
    const int d = blockIdx.x * 256 + threadIdx.x;
    const int c = blockIdx.y;
    const int z = blockIdx.z;
    const int br = z >> 1, b = z & 1;
    const float* Al = br ? Alb : Ala;
    float An[16];
#pragma unroll
    for (int i = 0; i < 4; i++) {
        float4 v = *(const float4*)&Al[(long)d * 16 + i * 4];
        An[i * 4] = -__expf(v.x); An[i * 4 + 1] = -__expf(v.y);
        An[i * 4 + 2] = -__expf(v.z); An[i * 4 + 3] = -__expf(v.w);
    }
    const float Dd = (br ? Db : Da)[d];
    const long lbase = (long)z * LQ + (long)c * CH;
    const _Float16* ub = ut + lbase * DI + d;
    const _Float16* db = dlt + lbase * DI + d;
    const float* bc = dbl + lbase * E80 + 48;
    const float* Hp = h0 + (((long)z * NC + c) * DI + d) * 16;
    float h[16];
#pragma unroll
    for (int i = 0; i < 4; i++) {
        float4 v = *(const float4*)&Hp[i * 4];
        h[i * 4] = v.x; h[i * 4 + 1] = v.y; h[i * 4 + 2] = v.z; h[i * 4 + 3] = v.w;
    }
    _Float16* yo = br ? yb : ya;

    for (int t0 = 0; t0 < CH; t0 += 8) {
        _Float16 uu[8], dd[8];
#pragma unroll
        for (int j = 0; j < 8; j++) {
            uu[j] = ub[(long)(t0 + j) * DI];
            dd[j] = db[(long)(t0 + j) * DI];
        }
#pragma unroll
        for (int j = 0; j < 8; j++) {
            float dl = (float)dd[j];
            float u  = (float)uu[j];
            float du = dl * u;
            const float* Bp = bc + (long)(t0 + j) * E80;
            float Bv[16], Cv[16];
#pragma unroll
            for (int i = 0; i < 4; i++) {
                float4 v = *(const float4*)&Bp[i * 4];
                Bv[i * 4] = v.x; Bv[i * 4 + 1] = v.y;
                Bv[i * 4 + 2] = v.z; Bv[i * 4 + 3] = v.w;
                float4 w2 = *(const float4*)&Bp[16 + i * 4];
                Cv[i * 4] = w2.x; Cv[i * 4 + 1] = w2.y;
                Cv[i * 4 + 2] = w2.z; Cv[i * 4 + 3] = w2.w;
            }
            float y = u * Dd;
#pragma unroll
            for (int n = 0; n < 16; n++) {
                h[n] = fmaf(__expf(dl * An[n]), h[n], du * Bv[n]);
                y = fmaf(h[n], Cv[n], y);
            }
            int t = c * CH + t0 + j;
            long lorig = br ? (LQ - 1 - t) : t;
            yo[((long)b * LQ + lorig) * DI + d] = (_Float16)y;
        }
    }
}

// ---------------------------------------------------------------------------
// yf = (ya + yb) * silu(z)  -> fp16 [b][l][d]. 8 elements/thread.
// ---------------------------------------------------------------------------
__global__ __launch_bounds__(256)
void fuse_y(const _Float16* __restrict__ ya, const _Float16* __restrict__ yb,
            const _Float16* __restrict__ zt, _Float16* __restrict__ yf)
{
    long i = ((long)blockIdx.x * 256 + threadIdx.x) * 8;
    half8 a = *(const half8*)(ya + i);
    half8 b = *(const half8*)(yb + i);
    half8 zz = *(const half8*)(zt + i);
    half8 o;
#pragma unroll
    for (int j = 0; j < 8; j++) {
        float y = (float)a[j] + (float)b[j];
        float zv = (float)zz[j];
        o[j] = (_Float16)(y * (zv / (1.f + __expf(-zv))));
    }
    *(half8*)(yf + i) = o;
}

// ---------------------------------------------------------------------------
extern "C" void kernel_launch(void* const* d_in, const int* in_sizes, int n_in,
                              void* d_out, int out_size, void* d_ws, size_t ws_size,
                              hipStream_t stream)
{
    const float* hs  = (const float*)d_in[0];
    const float* Wi  = (const float*)d_in[1];
    const float* Wo  = (const float*)d_in[2];
    const float* cwa = (const float*)d_in[3];
    const float* cba = (const float*)d_in[4];
    const float* cwb = (const float*)d_in[5];
    const float* cbb = (const float*)d_in[6];
    const float* xpa = (const float*)d_in[7];
    const float* xpb = (const float*)d_in[8];
    const float* dwa = (const float*)d_in[9];
    const float* dwb = (const float*)d_in[10];
    const float* dba = (const float*)d_in[11];
    const float* dbb = (const float*)d_in[12];
    const float* Ala = (const float*)d_in[13];
    const float* Alb = (const float*)d_in[14];
    const float* Da  = (const float*)d_in[15];
    const float* Db  = (const float*)d_in[16];
    float* out = (float*)d_out;

    float* ws = (float*)d_ws;
    // Region A (xz) is reused for dl_t/ya/yb after conv_silu_t + transpose_z.
    float*    xz   = ws;                                // [0 .. 25165824)
    _Float16* dl_t = (_Float16*)ws;
    _Float16* ya   = (_Float16*)(ws + 12582912);
    _Float16* yb   = (_Float16*)(ws + 18874368);
    float*    dbl  = ws + 25165824;                     // [.. 26476544)
    _Float16* u_t  = (_Float16*)(ws + 26476544);        // [.. 39059456)
    _Float16* yf   = (_Float16*)(ws + 26476544);        // aliases u_t (dead after p3)
    _Float16* z_t  = (_Float16*)(ws + 39059456);        // [.. 45350912)
    float*    Sdl  = ws + 45350912;                     // [.. 45547520)
    float*    Hloc = ws + 45547520;                     // [.. 48693248)
    float*    h0   = ws + 48693248;                     // [.. 51838976)
    _Float16* hsb  = (_Float16*)(ws + 45350912);        // aliases Sdl/Hloc (dead pre-scan)
    _Float16* Wib  = (_Float16*)(ws + 48496640);        // [..49676288) (dead pre-scan)
    _Float16* xpw  = (_Float16*)(ws + 49676288);        // [..49799168) (dead pre-scan)
    _Float16* Wob  = (_Float16*)(ws + 45350912);        // aliases Sdl (packed AFTER scan_p3)
    // peak footprint: 51,838,976 floats = 207.36 MB (== R3/R6 passing layout)

    // 0) fp16 packs
    pack_fp16<<<6144, 256, 0, stream>>>(hs, hsb);              // 2*4096*768
    pack_fp16<<<2304, 256, 0, stream>>>(Wi, Wib);              // 3072*768
    pack_fp16<<<120, 256, 0, stream>>>(xpa, xpw);              // 80*1536
    pack_fp16<<<120, 256, 0, stream>>>(xpb, xpw + 122880);     // 80*1536
    // 1) in_proj (MFMA): xz[b,e,l] = sum_d Wi[e,d]*hs[b,l,d]
    gemm_mfma<<<dim3(32, 24, 2), 256, 0, stream>>>(
        Wib, hsb, xz, DM, DM, DM, LQ,
        0L, (long)LQ * DM, (long)2 * DI * LQ);
    // 2) conv+silu with transpose -> u_t fp16 [z][l][d]
    conv_silu_t<<<dim3(64, 24, 4), 256, 0, stream>>>(xz, cwa, cba, cwb, cbb, u_t);
    // 3) x_proj (MFMA): dbl = u_t @ xpw^T
    xproj_mfma<<<dim3(64, 4), 256, 0, stream>>>(u_t, xpw, dbl);
    // 4) z transpose to fp16 [l][d]   (last reader of xz)
    transpose_z<<<dim3(64, 24, 2), 256, 0, stream>>>(xz, z_t);
    // 5) delta (fp16 [t][d]; overwrites xz region)
    delta_kernel<<<dim3(64, 6, 4), 256, 0, stream>>>(dbl, dwa, dwb, dba, dbb, dl_t);
    // 6) chunked scan
    scan_p1<<<dim3(6, NC, 4), 256, 0, stream>>>(u_t, dl_t, dbl, Ala, Alb, Sdl, Hloc);
    scan_p2<<<dim3(96, 4), 256, 0, stream>>>(Sdl, Hloc, Ala, Alb, h0);
    scan_p3<<<dim3(6, NC, 4), 256, 0, stream>>>(u_t, dl_t, dbl, h0, Ala, Alb, Da, Db, ya, yb);
    // 7) pack Wo (Sdl dead now); fuse (ya+yb)*silu(z) -> yf (fp16)
    pack_fp16<<<1152, 256, 0, stream>>>(Wo, Wob);   // 768*1536
    fuse_y<<<6144, 256, 0, stream>>>(ya, yb, z_t, yf);
    // 8) out_proj (MFMA): out[b,l,o] = sum_d yf[b,l,d]*Wo[o,d]
    gemm_mfma<<<dim3(6, 32, 2), 256, 0, stream>>>(
        yf, Wob, out, DI, DI, DI, DM,
        (long)LQ * DI, 0L, (long)LQ * DM);
}

// Round 9
// 639.003 us; speedup vs baseline: 3.3747x; 1.0293x over previous
//
#include <hip/hip_runtime.h>
#include <math.h>

#define BQ 2
#define LQ 4096
#define DM 768
#define DI 1536
#define DS 16
#define E80 80   // DTR + 2*DS
#define NC 32
#define CH 128   // LQ / NC

typedef _Float16 half8 __attribute__((ext_vector_type(8)));
typedef _Float16 half4v __attribute__((ext_vector_type(4)));
typedef float f32x4 __attribute__((ext_vector_type(4)));

__device__ __forceinline__ ushort f2h_bits(float x) {
    return __builtin_bit_cast(ushort, (_Float16)x);
}

// ---------------------------------------------------------------------------
// f32 -> fp16 pack (n divisible by 1024; grid = n/1024)
// ---------------------------------------------------------------------------
__global__ __launch_bounds__(256)
void pack_fp16(const float* __restrict__ src, _Float16* __restrict__ dst)
{
    long i = ((long)blockIdx.x * 256 + threadIdx.x) * 4;
    float4 v = *(const float4*)(src + i);
    half4v o = {(_Float16)v.x, (_Float16)v.y, (_Float16)v.z, (_Float16)v.w};
    *(half4v*)(dst + i) = o;
}

// ---------------------------------------------------------------------------
// dt_proj weights -> fp16 [br][d][64], zero-padded k=48..63. grid 12x256.
// ---------------------------------------------------------------------------
__global__ __launch_bounds__(256)
void pack_dtw(const float* __restrict__ dwa, const float* __restrict__ dwb,
              _Float16* __restrict__ dtw)
{
    int idx = blockIdx.x * 256 + threadIdx.x;   // 0 .. 2*DI-1
    int br = idx / DI, d = idx % DI;
    const float* W = (br ? dwb : dwa) + (long)d * 48;
    _Float16* o = dtw + (long)idx * 64;
#pragma unroll
    for (int k = 0; k < 48; k++) o[k] = (_Float16)W[k];
#pragma unroll
    for (int k = 48; k < 64; k++) o[k] = (_Float16)0.f;
}

// ---------------------------------------------------------------------------
// MFMA NT GEMM (fp16 in, f32 out): C[m,n] = sum_k A[m,k]*B[n,k].
// 128x128 tile, BK=64. Fragment-ordered LDS (uint4): [frag][lane] x16B.
// NOTE: all __shared__ arrays in this file are 32-bit+ types ON PURPOSE —
// 16-bit-typed shared arrays correlate 6/6 with container-killing faults
// (R4/R5/R7 died, R2/R3/R6/R8 passed).
// ---------------------------------------------------------------------------
__global__ __launch_bounds__(256)
void gemm_mfma(const _Float16* __restrict__ Ah, const _Float16* __restrict__ Bh,
               float* __restrict__ C, int K, int ldA, int ldB, int ldC,
               long strideA, long strideB, long strideC)
{
    __shared__ uint4 Af[16][64];
    __shared__ uint4 Bf[16][64];
    const int bz = blockIdx.z;
    const _Float16* Ab = Ah + (long)bz * strideA;
    const _Float16* Bb = Bh + (long)bz * strideB;
    float* Cb = C + (long)bz * strideC;
    const int m0 = blockIdx.y * 128, n0 = blockIdx.x * 128;
    const int tid = threadIdx.x, w = tid >> 6, lane = tid & 63;
    const int mh = w & 1, nh = w >> 1;

    const _Float16* asrc[4];
    const _Float16* bsrc[4];
#pragma unroll
    for (int i = 0; i < 4; i++) {
        int f = w * 4 + i;
        int ks = f >> 3, t = f & 7;
        asrc[i] = Ab + (long)(m0 + t * 16 + (lane & 15)) * ldA + ks * 32 + (lane >> 4) * 8;
        bsrc[i] = Bb + (long)(n0 + t * 16 + (lane & 15)) * ldB + ks * 32 + (lane >> 4) * 8;
    }

    f32x4 acc[4][4];
#pragma unroll
    for (int i = 0; i < 4; i++)
#pragma unroll
        for (int j = 0; j < 4; j++) acc[i][j] = {0.f, 0.f, 0.f, 0.f};

    for (int k0 = 0; k0 < K; k0 += 64) {
#pragma unroll
        for (int i = 0; i < 4; i++) {
            Af[w * 4 + i][lane] = *(const uint4*)asrc[i];
            Bf[w * 4 + i][lane] = *(const uint4*)bsrc[i];
            asrc[i] += 64; bsrc[i] += 64;
        }
        __syncthreads();
#pragma unroll
        for (int ks = 0; ks < 2; ks++) {
            uint4 au[4], bu[4];
#pragma unroll
            for (int i = 0; i < 4; i++) {
                au[i] = Af[ks * 8 + mh * 4 + i][lane];
                bu[i] = Bf[ks * 8 + nh * 4 + i][lane];
            }
#pragma unroll
            for (int i = 0; i < 4; i++) {
                half8 av = __builtin_bit_cast(half8, au[i]);
#pragma unroll
                for (int j = 0; j < 4; j++) {
                    half8 bv = __builtin_bit_cast(half8, bu[j]);
                    acc[i][j] = __builtin_amdgcn_mfma_f32_16x16x32_f16(
                        av, bv, acc[i][j], 0, 0, 0);
                }
            }
        }
        __syncthreads();
    }
    const int r0 = (lane >> 4) * 4, cn = lane & 15;
#pragma unroll
    for (int i = 0; i < 4; i++) {
        int mrow = m0 + (mh * 4 + i) * 16 + r0;
#pragma unroll
        for (int j = 0; j < 4; j++) {
            int col = n0 + (nh * 4 + j) * 16 + cn;
#pragma unroll
            for (int r = 0; r < 4; r++)
                Cb[(long)(mrow + r) * ldC + col] = acc[i][j][r];
        }
    }
}

// ---------------------------------------------------------------------------
// Depthwise conv(k=4)+SiLU with transpose: xz x-half [b][d][l] fp32 ->
// u_t fp16 [z][l][d]. br=1 consumes reversed sequence.
// ---------------------------------------------------------------------------
__global__ __launch_bounds__(256)
void conv_silu_t(const float* __restrict__ xz,
                 const float* __restrict__ cwa, const float* __restrict__ cba,
                 const float* __restrict__ cwb, const float* __restrict__ cbb,
                 _Float16* __restrict__ ut)
{
    __shared__ float lraw[64][67];
    __shared__ float cu[64][72];
    __shared__ float lcw[64][5];
    const int l0 = blockIdx.x * 64, d0 = blockIdx.y * 64;
    const int z = blockIdx.z;
    const int br = z >> 1, b = z & 1;
    const float* xb = xz + ((long)b * 2 * DI + d0) * LQ;
    const float* CW = br ? cwb : cwa;
    const float* CB = br ? cbb : cba;
    const int tid = threadIdx.x;

    {
        int dd = tid >> 2, k = tid & 3;
        lcw[dd][k] = CW[(d0 + dd) * 4 + k];
        if (tid < 64) lcw[tid][4] = CB[d0 + tid];
    }
    for (int i = tid; i < 64 * 67; i += 256) {
        int dd = i / 67, cc = i % 67;
        int src = l0 - 3 + cc;
        float v = 0.f;
        if (src >= 0)
            v = xb[(long)dd * LQ + (br ? (LQ - 1 - src) : src)];
        lraw[dd][cc] = v;
    }
    __syncthreads();
#pragma unroll
    for (int q = 0; q < 16; q++) {
        int o = tid + q * 256;
        int dd = o & 63, ll = o >> 6;
        float a = lcw[dd][4];
        a = fmaf(lraw[dd][ll + 0], lcw[dd][0], a);
        a = fmaf(lraw[dd][ll + 1], lcw[dd][1], a);
        a = fmaf(lraw[dd][ll + 2], lcw[dd][2], a);
        a = fmaf(lraw[dd][ll + 3], lcw[dd][3], a);
        cu[ll][dd] = a * (1.f / (1.f + __expf(-a)));
    }
    __syncthreads();
    const int dg = (tid & 7) * 8;
#pragma unroll
    for (int p = 0; p < 2; p++) {
        int ll = (tid >> 3) + p * 32;
        float4 v0 = *(const float4*)&cu[ll][dg];
        float4 v1 = *(const float4*)&cu[ll][dg + 4];
        uint4 o;
        o.x = f2h_bits(v0.x) | ((unsigned)f2h_bits(v0.y) << 16);
        o.y = f2h_bits(v0.z) | ((unsigned)f2h_bits(v0.w) << 16);
        o.z = f2h_bits(v1.x) | ((unsigned)f2h_bits(v1.y) << 16);
        o.w = f2h_bits(v1.z) | ((unsigned)f2h_bits(v1.w) << 16);
        *(uint4*)(ut + ((long)z * LQ + l0 + ll) * DI + d0 + dg) = o;
    }
}

// ---------------------------------------------------------------------------
// x_proj MFMA GEMM: dbl[z][l][e] = sum_d u_t[z][l][d] * xpw[br][e][d].
// ---------------------------------------------------------------------------
__global__ __launch_bounds__(256)
void xproj_mfma(const _Float16* __restrict__ ut, const _Float16* __restrict__ xpw,
                float* __restrict__ dbl)
{
    __shared__ uint4 Af[8][64];
    __shared__ uint4 Bf[10][64];
    const int m0 = blockIdx.x * 64;
    const int z = blockIdx.y;
    const _Float16* A = ut + (long)z * LQ * DI;
    const _Float16* W = xpw + (long)(z >> 1) * E80 * DI;
    float* out = dbl + (long)z * LQ * E80;
    const int tid = threadIdx.x, w = tid >> 6, lane = tid & 63;

    f32x4 acc[5];
#pragma unroll
    for (int j = 0; j < 5; j++) acc[j] = {0.f, 0.f, 0.f, 0.f};

    for (int k0 = 0; k0 < DI; k0 += 64) {
#pragma unroll
        for (int i = 0; i < 2; i++) {
            int f = w + i * 4;
            int row = m0 + (f & 3) * 16 + (lane & 15);
            int koff = k0 + (f >> 2) * 32 + (lane >> 4) * 8;
            Af[f][lane] = *(const uint4*)(A + (long)row * DI + koff);
        }
        for (int i = tid; i < 640; i += 256) {
            int f = i >> 6, ln = i & 63;
            int e = (f >> 1) * 16 + (ln & 15);
            int koff = k0 + (f & 1) * 32 + (ln >> 4) * 8;
            Bf[f][ln] = *(const uint4*)(W + (long)e * DI + koff);
        }
        __syncthreads();
#pragma unroll
        for (int ks = 0; ks < 2; ks++) {
            half8 av = __builtin_bit_cast(half8, Af[ks * 4 + w][lane]);
#pragma unroll
            for (int j = 0; j < 5; j++) {
                half8 bv = __builtin_bit_cast(half8, Bf[j * 2 + ks][lane]);
                acc[j] = __builtin_amdgcn_mfma_f32_16x16x32_f16(av, bv, acc[j], 0, 0, 0);
            }
        }
        __syncthreads();
    }
    const int r0 = (lane >> 4) * 4, cn = lane & 15;
    const int row = m0 + w * 16 + r0;
#pragma unroll
    for (int j = 0; j < 5; j++)
#pragma unroll
        for (int r = 0; r < 4; r++)
            out[(long)(row + r) * E80 + j * 16 + cn] = acc[j][r];
}

// ---------------------------------------------------------------------------
// delta MFMA GEMM + softplus: dl_t[z][l][d] =
//   softplus( sum_k dbl[z][l][k<48] * dtw[br][d][k] + bias[d] ), K padded 64.
// 64(l) x 128(d) tile, single K pass. Grid (LQ/64, DI/128, 4).
// ---------------------------------------------------------------------------
__global__ __launch_bounds__(256)
void delta_mfma(const float* __restrict__ dbl, const _Float16* __restrict__ dtw,
                const float* __restrict__ dba, const float* __restrict__ dbb,
                _Float16* __restrict__ dlt)
{
    __shared__ uint4 Af[8][64];    // f = mtile*2 + ks
    __shared__ uint4 Bf[16][64];   // f = ntile*2 + ks
    const int m0 = blockIdx.x * 64;
    const int n0 = blockIdx.y * 128;
    const int z  = blockIdx.z;
    const float* bias = (z >> 1) ? dbb : dba;
    const float* Ab = dbl + (long)z * LQ * E80;
    const _Float16* Wb = dtw + (long)(z >> 1) * DI * 64;
    _Float16* ob = dlt + (long)z * LQ * DI;
    const int tid = threadIdx.x, w = tid >> 6, lane = tid & 63;

    // stage A: 8 frags, f32->f16 convert, zero for k>=48
#pragma unroll
    for (int i = 0; i < 2; i++) {
        int s = tid + i * 256;
        int f = s >> 6, ln = s & 63;
        int mt = f >> 1, ks = f & 1;
        int row = m0 + mt * 16 + (ln & 15);
        int koff = ks * 32 + (ln >> 4) * 8;
        uint4 o = {0u, 0u, 0u, 0u};
        if (koff < 48) {
            const float* p = Ab + (long)row * E80 + koff;
            float4 v0 = *(const float4*)p;
            float4 v1 = *(const float4*)(p + 4);
            o.x = f2h_bits(v0.x) | ((unsigned)f2h_bits(v0.y) << 16);
            o.y = f2h_bits(v0.z) | ((unsigned)f2h_bits(v0.w) << 16);
            o.z = f2h_bits(v1.x) | ((unsigned)f2h_bits(v1.y) << 16);
            o.w = f2h_bits(v1.z) | ((unsigned)f2h_bits(v1.w) << 16);
        }
        Af[f][ln] = o;
    }
    // stage B: 16 frags from pre-padded fp16 weights
#pragma unroll
    for (int i = 0; i < 4; i++) {
        int s = tid + i * 256;
        int f = s >> 6, ln = s & 63;
        int nt = f >> 1, ks = f & 1;
        int d = n0 + nt * 16 + (ln & 15);
        int koff = ks * 32 + (ln >> 4) * 8;
        Bf[f][ln] = *(const uint4*)(Wb + (long)d * 64 + koff);
    }
    __syncthreads();

    f32x4 acc[8];
#pragma unroll
    for (int j = 0; j < 8; j++) acc[j] = {0.f, 0.f, 0.f, 0.f};
#pragma unroll
    for (int ks = 0; ks < 2; ks++) {
        half8 av = __builtin_bit_cast(half8, Af[w * 2 + ks][lane]);
#pragma unroll
        for (int j = 0; j < 8; j++) {
            half8 bv = __builtin_bit_cast(half8, Bf[j * 2 + ks][lane]);
            acc[j] = __builtin_amdgcn_mfma_f32_16x16x32_f16(av, bv, acc[j], 0, 0, 0);
        }
    }
    const int r0 = (lane >> 4) * 4, cn = lane & 15;
    const int row = m0 + w * 16 + r0;
#pragma unroll
    for (int j = 0; j < 8; j++) {
        int d = n0 + j * 16 + cn;
        float bi = bias[d];
#pragma unroll
        for (int r = 0; r < 4; r++) {
            float a = acc[j][r] + bi;
            float sp = (a > 20.f) ? a : log1pf(__expf(a));
            ob[(long)(row + r) * DI + d] = (_Float16)sp;
        }
    }
}

// ---------------------------------------------------------------------------
// Transpose z-half of xz [b][DI..2DI][l] -> z_t fp16 [b][l][d].
// ---------------------------------------------------------------------------
__global__ __launch_bounds__(256)
void transpose_z(const float* __restrict__ xz, _Float16* __restrict__ zt)
{
    __shared__ float t[64][65];
    const int l0 = blockIdx.x * 64, d0 = blockIdx.y * 64, b = blockIdx.z;
    const float* src = xz + ((long)b * 2 * DI + DI + d0) * LQ + l0;
    const int tid = threadIdx.x;
    const int r = tid >> 4, c4 = (tid & 15) * 4;
#pragma unroll
    for (int i = 0; i < 4; i++) {
        float4 v = *(const float4*)&src[(long)(r + i * 16) * LQ + c4];
        t[c4 + 0][r + i * 16] = v.x; t[c4 + 1][r + i * 16] = v.y;
        t[c4 + 2][r + i * 16] = v.z; t[c4 + 3][r + i * 16] = v.w;
    }
    __syncthreads();
    const int l = tid >> 2, seg = (tid & 3) * 16;
    ushort tmp[16];
#pragma unroll
    for (int j = 0; j < 16; j++) tmp[j] = f2h_bits(t[l][seg + j]);
    uint4 p0, p1;
    p0.x = tmp[0] | (tmp[1] << 16);  p0.y = tmp[2] | (tmp[3] << 16);
    p0.z = tmp[4] | (tmp[5] << 16);  p0.w = tmp[6] | (tmp[7] << 16);
    p1.x = tmp[8] | (tmp[9] << 16);  p1.y = tmp[10] | (tmp[11] << 16);
    p1.z = tmp[12] | (tmp[13] << 16); p1.w = tmp[14] | (tmp[15] << 16);
    ushort* dst = (ushort*)(zt + ((long)b * LQ + l0 + l) * DI + d0 + seg);
    *(uint4*)dst = p0;
    *(uint4*)(dst + 8) = p1;
}

// ---------------------------------------------------------------------------
// Scan pass 1: per-chunk summaries (lane = channel, 16 states in VGPRs).
// ---------------------------------------------------------------------------
__global__ __launch_bounds__(256)
void scan_p1(const _Float16* __restrict__ ut, const _Float16* __restrict__ dlt,
             const float* __restrict__ dbl,
             const float* __restrict__ Ala, const float* __restrict__ Alb,
             float* __restrict__ Sdl, float* __restrict__ Hloc)
{
    const int d = blockIdx.x * 256 + threadIdx.x;
    const int c = blockIdx.y;
    const int z = blockIdx.z;
    const int br = z >> 1;
    const float* Al = br ? Alb : Ala;
    float An[16];
#pragma unroll
    for (int i = 0; i < 4; i++) {
        float4 v = *(const float4*)&Al[(long)d * 16 + i * 4];
        An[i * 4] = -__expf(v.x); An[i * 4 + 1] = -__expf(v.y);
        An[i * 4 + 2] = -__expf(v.z); An[i * 4 + 3] = -__expf(v.w);
    }
    const long lbase = (long)z * LQ + (long)c * CH;
    const _Float16* ub = ut + lbase * DI + d;
    const _Float16* db = dlt + lbase * DI + d;
    const float* bc = dbl + lbase * E80 + 48;

    float h[16];
#pragma unroll
    for (int n = 0; n < 16; n++) h[n] = 0.f;
    float sdl = 0.f;

    for (int t0 = 0; t0 < CH; t0 += 8) {
        _Float16 uu[8], dd[8];
#pragma unroll
        for (int j = 0; j < 8; j++) {
            uu[j] = ub[(long)(t0 + j) * DI];
            dd[j] = db[(long)(t0 + j) * DI];
        }
#pragma unroll
        for (int j = 0; j < 8; j++) {
            float dl = (float)dd[j];
            float u  = (float)uu[j];
            sdl += dl;
            float du = dl * u;
            const float* Bp = bc + (long)(t0 + j) * E80;
            float Bv[16];
#pragma unroll
            for (int i = 0; i < 4; i++) {
                float4 v = *(const float4*)&Bp[i * 4];
                Bv[i * 4] = v.x; Bv[i * 4 + 1] = v.y;
                Bv[i * 4 + 2] = v.z; Bv[i * 4 + 3] = v.w;
            }
#pragma unroll
            for (int n = 0; n < 16; n++)
                h[n] = fmaf(__expf(dl * An[n]), h[n], du * Bv[n]);
        }
    }
    Sdl[((long)z * NC + c) * DI + d] = sdl;
    float* Hp = Hloc + (((long)z * NC + c) * DI + d) * 16;
#pragma unroll
    for (int i = 0; i < 4; i++)
        *(float4*)&Hp[i * 4] = make_float4(h[i * 4], h[i * 4 + 1], h[i * 4 + 2], h[i * 4 + 3]);
}

// ---------------------------------------------------------------------------
// Scan pass 2: inter-chunk scan.
// ---------------------------------------------------------------------------
__global__ __launch_bounds__(256)
void scan_p2(const float* __restrict__ Sdl, const float* __restrict__ Hloc,
             const float* __restrict__ Ala, const float* __restrict__ Alb,
             float* __restrict__ h0)
{
    const int idx = blockIdx.x * 256 + threadIdx.x;
    const int z = blockIdx.y;
    const int d = idx >> 4, n = idx & 15;
    const float* Al = (z >> 1) ? Alb : Ala;
    const float An = -__expf(Al[(long)d * 16 + n]);
    float h = 0.f;
    for (int c = 0; c < NC; c++) {
        h0[((long)z * NC + c) * DI * 16 + idx] = h;
        float sdl = Sdl[((long)z * NC + c) * DI + d];
        float Hl = Hloc[((long)z * NC + c) * DI * 16 + idx];
        h = fmaf(__expf(An * sdl), h, Hl);
    }
}

// ---------------------------------------------------------------------------
// Scan pass 3: re-run chunks from h0, emit y (+D) fp16 [l][d], B pre-flipped.
// ---------------------------------------------------------------------------
__global__ __launch_bounds__(256)
void scan_p3(const _Float16* __restrict__ ut, const _Float16* __restrict__ dlt,
             const float* __restrict__ dbl, const float* __restrict__ h0,
             const float* __restrict__ Ala, const float* __restrict__ Alb,
             const float* __restrict__ Da, const float* __restrict__ Db,
             _Float16* __restrict__ ya, _Float16* __restrict__ yb)
{
    const int d = blockIdx.x * 256 + threadIdx.x;
    const int c = blockIdx.y;
    const int z = blockIdx.z;
    const int br = z >> 1, b = z & 1;
    const float* Al = br ? Alb : Ala;
    float An[16];
#pragma unroll
    for (int i = 0; i < 4; i++) {
        float4 v = *(const float4*)&Al[(long)d * 16 + i * 4];
        An[i * 4] = -__expf(v.x); An[i * 4 + 1] = -__expf(v.y);
        An[i * 4 + 2] = -__expf(v.z); An[i * 4 + 3] = -__expf(v.w);
    }
    const float Dd = (br ? Db : Da)[d];
    const long lbase = (long)z * LQ + (long)c * CH;
    const _Float16* ub = ut + lbase * DI + d;
    const _Float16* db = dlt + lbase * DI + d;
    const float* bc = dbl + lbase * E80 + 48;
    const float* Hp = h0 + (((long)z * NC + c) * DI + d) * 16;
    float h[16];
#pragma unroll
    for (int i = 0; i < 4; i++) {
        float4 v = *(const float4*)&Hp[i * 4];
        h[i * 4] = v.x; h[i * 4 + 1] = v.y; h[i * 4 + 2] = v.z; h[i * 4 + 3] = v.w;
    }
    _Float16* yo = br ? yb : ya;

    for (int t0 = 0; t0 < CH; t0 += 8) {
        _Float16 uu[8], dd[8];
#pragma unroll
        for (int j = 0; j < 8; j++) {
            uu[j] = ub[(long)(t0 + j) * DI];
            dd[j] = db[(long)(t0 + j) * DI];
        }
#pragma unroll
        for (int j = 0; j < 8; j++) {
            float dl = (float)dd[j];
            float u  = (float)uu[j];
            float du = dl * u;
            const float* Bp = bc + (long)(t0 + j) * E80;
            float Bv[16], Cv[16];
#pragma unroll
            for (int i = 0; i < 4; i++) {
                float4 v = *(const float4*)&Bp[i * 4];
                Bv[i * 4] = v.x; Bv[i * 4 + 1] = v.y;
                Bv[i * 4 + 2] = v.z; Bv[i * 4 + 3] = v.w;
                float4 w2 = *(const float4*)&Bp[16 + i * 4];
                Cv[i * 4] = w2.x; Cv[i * 4 + 1] = w2.y;
                Cv[i * 4 + 2] = w2.z; Cv[i * 4 + 3] = w2.w;
            }
            float y = u * Dd;
#pragma unroll
            for (int n = 0; n < 16; n++) {
                h[n] = fmaf(__expf(dl * An[n]), h[n], du * Bv[n]);
                y = fmaf(h[n], Cv[n], y);
            }
            int t = c * CH + t0 + j;
            long lorig = br ? (LQ - 1 - t) : t;
            yo[((long)b * LQ + lorig) * DI + d] = (_Float16)y;
        }
    }
}

// ---------------------------------------------------------------------------
// yf = (ya + yb) * silu(z)  -> fp16 [b][l][d]. 8 elements/thread.
// ---------------------------------------------------------------------------
__global__ __launch_bounds__(256)
void fuse_y(const _Float16* __restrict__ ya, const _Float16* __restrict__ yb,
            const _Float16* __restrict__ zt, _Float16* __restrict__ yf)
{
    long i = ((long)blockIdx.x * 256 + threadIdx.x) * 8;
    half8 a = *(const half8*)(ya + i);
    half8 b = *(const half8*)(yb + i);
    half8 zz = *(const half8*)(zt + i);
    half8 o;
#pragma unroll
    for (int j = 0; j < 8; j++) {
        float y = (float)a[j] + (float)b[j];
        float zv = (float)zz[j];
        o[j] = (_Float16)(y * (zv / (1.f + __expf(-zv))));
    }
    *(half8*)(yf + i) = o;
}

// ---------------------------------------------------------------------------
extern "C" void kernel_launch(void* const* d_in, const int* in_sizes, int n_in,
                              void* d_out, int out_size, void* d_ws, size_t ws_size,
                              hipStream_t stream)
{
    const float* hs  = (const float*)d_in[0];
    const float* Wi  = (const float*)d_in[1];
    const float* Wo  = (const float*)d_in[2];
    const float* cwa = (const float*)d_in[3];
    const float* cba = (const float*)d_in[4];
    const float* cwb = (const float*)d_in[5];
    const float* cbb = (const float*)d_in[6];
    const float* xpa = (const float*)d_in[7];
    const float* xpb = (const float*)d_in[8];
    const float* dwa = (const float*)d_in[9];
    const float* dwb = (const float*)d_in[10];
    const float* dba = (const float*)d_in[11];
    const float* dbb = (const float*)d_in[12];
    const float* Ala = (const float*)d_in[13];
    const float* Alb = (const float*)d_in[14];
    const float* Da  = (const float*)d_in[15];
    const float* Db  = (const float*)d_in[16];
    float* out = (float*)d_out;

    float* ws = (float*)d_ws;
    float*    xz   = ws;                                // [0 .. 25165824)
    _Float16* dl_t = (_Float16*)ws;
    _Float16* ya   = (_Float16*)(ws + 12582912);
    _Float16* yb   = (_Float16*)(ws + 18874368);
    float*    dbl  = ws + 25165824;                     // [.. 26476544)
    _Float16* u_t  = (_Float16*)(ws + 26476544);        // [.. 39059456)
    _Float16* yf   = (_Float16*)(ws + 26476544);        // aliases u_t (dead after p3)
    _Float16* z_t  = (_Float16*)(ws + 39059456);        // [.. 45350912)
    float*    Sdl  = ws + 45350912;                     // [.. 45547520)
    float*    Hloc = ws + 45547520;                     // [.. 48693248)
    float*    h0   = ws + 48693248;                     // [.. 51838976)
    _Float16* hsb  = (_Float16*)(ws + 45350912);        // dead pre-scan
    _Float16* Wib  = (_Float16*)(ws + 48496640);        // dead pre-scan
    _Float16* xpw  = (_Float16*)(ws + 49676288);        // dead pre-scan
    _Float16* dtw  = (_Float16*)(ws + 49799168);        // [..49897472) dead pre-scan
    _Float16* Wob  = (_Float16*)(ws + 45350912);        // packed AFTER scan_p3
    // peak footprint: 51,838,976 floats = 207.36 MB (== R3/R6/R8 passing layout)

    // 0) fp16 packs
    pack_fp16<<<6144, 256, 0, stream>>>(hs, hsb);              // 2*4096*768
    pack_fp16<<<2304, 256, 0, stream>>>(Wi, Wib);              // 3072*768
    pack_fp16<<<120, 256, 0, stream>>>(xpa, xpw);              // 80*1536
    pack_fp16<<<120, 256, 0, stream>>>(xpb, xpw + 122880);     // 80*1536
    pack_dtw<<<12, 256, 0, stream>>>(dwa, dwb, dtw);           // 2*1536*64 padded
    // 1) in_proj (MFMA)
    gemm_mfma<<<dim3(32, 24, 2), 256, 0, stream>>>(
        Wib, hsb, xz, DM, DM, DM, LQ,
        0L, (long)LQ * DM, (long)2 * DI * LQ);
    // 2) conv+silu with transpose -> u_t fp16 [z][l][d]
    conv_silu_t<<<dim3(64, 24, 4), 256, 0, stream>>>(xz, cwa, cba, cwb, cbb, u_t);
    // 3) x_proj (MFMA)
    xproj_mfma<<<dim3(64, 4), 256, 0, stream>>>(u_t, xpw, dbl);
    // 4) z transpose (last reader of xz)
    transpose_z<<<dim3(64, 24, 2), 256, 0, stream>>>(xz, z_t);
    // 5) delta via MFMA + fused softplus (overwrites xz region)
    delta_mfma<<<dim3(64, 12, 4), 256, 0, stream>>>(dbl, dtw, dba, dbb, dl_t);
    // 6) chunked scan
    scan_p1<<<dim3(6, NC, 4), 256, 0, stream>>>(u_t, dl_t, dbl, Ala, Alb, Sdl, Hloc);
    scan_p2<<<dim3(96, 4), 256, 0, stream>>>(Sdl, Hloc, Ala, Alb, h0);
    scan_p3<<<dim3(6, NC, 4), 256, 0, stream>>>(u_t, dl_t, dbl, h0, Ala, Alb, Da, Db, ya, yb);
    // 7) pack Wo (Sdl dead now); fuse (ya+yb)*silu(z)
    pack_fp16<<<1152, 256, 0, stream>>>(Wo, Wob);   // 768*1536
    fuse_y<<<6144, 256, 0, stream>>>(ya, yb, z_t, yf);
    // 8) out_proj (MFMA)
    gemm_mfma<<<dim3(6, 32, 2), 256, 0, stream>>>(
        yf, Wob, out, DI, DI, DI, DM,
        (long)LQ * DI, 0L, (long)LQ * DM);
}

// Round 10
// 606.507 us; speedup vs baseline: 3.5555x; 1.0536x over previous
//
#include <hip/hip_runtime.h>
#include <math.h>

#define BQ 2
#define LQ 4096
#define DM 768
#define DI 1536
#define DS 16
#define E80 80   // DTR + 2*DS
#define NC 32
#define CH 128   // LQ / NC

typedef _Float16 half8 __attribute__((ext_vector_type(8)));
typedef _Float16 half4v __attribute__((ext_vector_type(4)));
typedef float f32x4 __attribute__((ext_vector_type(4)));

__device__ __forceinline__ ushort f2h_bits(float x) {
    return __builtin_bit_cast(ushort, (_Float16)x);
}

// ---------------------------------------------------------------------------
// f32 -> fp16 pack (n divisible by 1024; grid = n/1024)
// ---------------------------------------------------------------------------
__global__ __launch_bounds__(256)
void pack_fp16(const float* __restrict__ src, _Float16* __restrict__ dst)
{
    long i = ((long)blockIdx.x * 256 + threadIdx.x) * 4;
    float4 v = *(const float4*)(src + i);
    half4v o = {(_Float16)v.x, (_Float16)v.y, (_Float16)v.z, (_Float16)v.w};
    *(half4v*)(dst + i) = o;
}

// ---------------------------------------------------------------------------
// dt_proj weights -> fp16 [br][d][64], zero-padded k=48..63. grid 12x256.
// ---------------------------------------------------------------------------
__global__ __launch_bounds__(256)
void pack_dtw(const float* __restrict__ dwa, const float* __restrict__ dwb,
              _Float16* __restrict__ dtw)
{
    int idx = blockIdx.x * 256 + threadIdx.x;   // 0 .. 2*DI-1
    int br = idx / DI, d = idx % DI;
    const float* W = (br ? dwb : dwa) + (long)d * 48;
    _Float16* o = dtw + (long)idx * 64;
#pragma unroll
    for (int k = 0; k < 48; k++) o[k] = (_Float16)W[k];
#pragma unroll
    for (int k = 48; k < 64; k++) o[k] = (_Float16)0.f;
}

// ---------------------------------------------------------------------------
// MFMA NT GEMM (fp16 in, f32 out): C[m,n] = sum_k A[m,k]*B[n,k].
// 128x128 tile, BK=64. Fragment-ordered LDS (uint4): [frag][lane] x16B.
// NOTE: all __shared__ arrays in this file are 32-bit+ types ON PURPOSE —
// 16-bit-typed shared arrays correlate with container-killing faults
// (R4/R5/R7 died, R2/R3/R6/R8/R9 passed).
// ---------------------------------------------------------------------------
__global__ __launch_bounds__(256)
void gemm_mfma(const _Float16* __restrict__ Ah, const _Float16* __restrict__ Bh,
               float* __restrict__ C, int K, int ldA, int ldB, int ldC,
               long strideA, long strideB, long strideC)
{
    __shared__ uint4 Af[16][64];
    __shared__ uint4 Bf[16][64];
    const int bz = blockIdx.z;
    const _Float16* Ab = Ah + (long)bz * strideA;
    const _Float16* Bb = Bh + (long)bz * strideB;
    float* Cb = C + (long)bz * strideC;
    const int m0 = blockIdx.y * 128, n0 = blockIdx.x * 128;
    const int tid = threadIdx.x, w = tid >> 6, lane = tid & 63;
    const int mh = w & 1, nh = w >> 1;

    const _Float16* asrc[4];
    const _Float16* bsrc[4];
#pragma unroll
    for (int i = 0; i < 4; i++) {
        int f = w * 4 + i;
        int ks = f >> 3, t = f & 7;
        asrc[i] = Ab + (long)(m0 + t * 16 + (lane & 15)) * ldA + ks * 32 + (lane >> 4) * 8;
        bsrc[i] = Bb + (long)(n0 + t * 16 + (lane & 15)) * ldB + ks * 32 + (lane >> 4) * 8;
    }

    f32x4 acc[4][4];
#pragma unroll
    for (int i = 0; i < 4; i++)
#pragma unroll
        for (int j = 0; j < 4; j++) acc[i][j] = {0.f, 0.f, 0.f, 0.f};

    for (int k0 = 0; k0 < K; k0 += 64) {
#pragma unroll
        for (int i = 0; i < 4; i++) {
            Af[w * 4 + i][lane] = *(const uint4*)asrc[i];
            Bf[w * 4 + i][lane] = *(const uint4*)bsrc[i];
            asrc[i] += 64; bsrc[i] += 64;
        }
        __syncthreads();
#pragma unroll
        for (int ks = 0; ks < 2; ks++) {
            uint4 au[4], bu[4];
#pragma unroll
            for (int i = 0; i < 4; i++) {
                au[i] = Af[ks * 8 + mh * 4 + i][lane];
                bu[i] = Bf[ks * 8 + nh * 4 + i][lane];
            }
#pragma unroll
            for (int i = 0; i < 4; i++) {
                half8 av = __builtin_bit_cast(half8, au[i]);
#pragma unroll
                for (int j = 0; j < 4; j++) {
                    half8 bv = __builtin_bit_cast(half8, bu[j]);
                    acc[i][j] = __builtin_amdgcn_mfma_f32_16x16x32_f16(
                        av, bv, acc[i][j], 0, 0, 0);
                }
            }
        }
        __syncthreads();
    }
    const int r0 = (lane >> 4) * 4, cn = lane & 15;
#pragma unroll
    for (int i = 0; i < 4; i++) {
        int mrow = m0 + (mh * 4 + i) * 16 + r0;
#pragma unroll
        for (int j = 0; j < 4; j++) {
            int col = n0 + (nh * 4 + j) * 16 + cn;
#pragma unroll
            for (int r = 0; r < 4; r++)
                Cb[(long)(mrow + r) * ldC + col] = acc[i][j][r];
        }
    }
}

// ---------------------------------------------------------------------------
// Depthwise conv(k=4)+SiLU with transpose: xz x-half [b][d][l] fp32 ->
// u_t fp16 [z][l][d]. br=1 consumes reversed sequence.
// ---------------------------------------------------------------------------
__global__ __launch_bounds__(256)
void conv_silu_t(const float* __restrict__ xz,
                 const float* __restrict__ cwa, const float* __restrict__ cba,
                 const float* __restrict__ cwb, const float* __restrict__ cbb,
                 _Float16* __restrict__ ut)
{
    __shared__ float lraw[64][67];
    __shared__ float cu[64][72];
    __shared__ float lcw[64][5];
    const int l0 = blockIdx.x * 64, d0 = blockIdx.y * 64;
    const int z = blockIdx.z;
    const int br = z >> 1, b = z & 1;
    const float* xb = xz + ((long)b * 2 * DI + d0) * LQ;
    const float* CW = br ? cwb : cwa;
    const float* CB = br ? cbb : cba;
    const int tid = threadIdx.x;

    {
        int dd = tid >> 2, k = tid & 3;
        lcw[dd][k] = CW[(d0 + dd) * 4 + k];
        if (tid < 64) lcw[tid][4] = CB[d0 + tid];
    }
    for (int i = tid; i < 64 * 67; i += 256) {
        int dd = i / 67, cc = i % 67;
        int src = l0 - 3 + cc;
        float v = 0.f;
        if (src >= 0)
            v = xb[(long)dd * LQ + (br ? (LQ - 1 - src) : src)];
        lraw[dd][cc] = v;
    }
    __syncthreads();
#pragma unroll
    for (int q = 0; q < 16; q++) {
        int o = tid + q * 256;
        int dd = o & 63, ll = o >> 6;
        float a = lcw[dd][4];
        a = fmaf(lraw[dd][ll + 0], lcw[dd][0], a);
        a = fmaf(lraw[dd][ll + 1], lcw[dd][1], a);
        a = fmaf(lraw[dd][ll + 2], lcw[dd][2], a);
        a = fmaf(lraw[dd][ll + 3], lcw[dd][3], a);
        cu[ll][dd] = a * (1.f / (1.f + __expf(-a)));
    }
    __syncthreads();
    const int dg = (tid & 7) * 8;
#pragma unroll
    for (int p = 0; p < 2; p++) {
        int ll = (tid >> 3) + p * 32;
        float4 v0 = *(const float4*)&cu[ll][dg];
        float4 v1 = *(const float4*)&cu[ll][dg + 4];
        uint4 o;
        o.x = f2h_bits(v0.x) | ((unsigned)f2h_bits(v0.y) << 16);
        o.y = f2h_bits(v0.z) | ((unsigned)f2h_bits(v0.w) << 16);
        o.z = f2h_bits(v1.x) | ((unsigned)f2h_bits(v1.y) << 16);
        o.w = f2h_bits(v1.z) | ((unsigned)f2h_bits(v1.w) << 16);
        *(uint4*)(ut + ((long)z * LQ + l0 + ll) * DI + d0 + dg) = o;
    }
}

// ---------------------------------------------------------------------------
// x_proj MFMA GEMM: dbl[z][l][e] = sum_d u_t[z][l][d] * xpw[br][e][d].
// ---------------------------------------------------------------------------
__global__ __launch_bounds__(256)
void xproj_mfma(const _Float16* __restrict__ ut, const _Float16* __restrict__ xpw,
                float* __restrict__ dbl)
{
    __shared__ uint4 Af[8][64];
    __shared__ uint4 Bf[10][64];
    const int m0 = blockIdx.x * 64;
    const int z = blockIdx.y;
    const _Float16* A = ut + (long)z * LQ * DI;
    const _Float16* W = xpw + (long)(z >> 1) * E80 * DI;
    float* out = dbl + (long)z * LQ * E80;
    const int tid = threadIdx.x, w = tid >> 6, lane = tid & 63;

    f32x4 acc[5];
#pragma unroll
    for (int j = 0; j < 5; j++) acc[j] = {0.f, 0.f, 0.f, 0.f};

    for (int k0 = 0; k0 < DI; k0 += 64) {
#pragma unroll
        for (int i = 0; i < 2; i++) {
            int f = w + i * 4;
            int row = m0 + (f & 3) * 16 + (lane & 15);
            int koff = k0 + (f >> 2) * 32 + (lane >> 4) * 8;
            Af[f][lane] = *(const uint4*)(A + (long)row * DI + koff);
        }
        for (int i = tid; i < 640; i += 256) {
            int f = i >> 6, ln = i & 63;
            int e = (f >> 1) * 16 + (ln & 15);
            int koff = k0 + (f & 1) * 32 + (ln >> 4) * 8;
            Bf[f][ln] = *(const uint4*)(W + (long)e * DI + koff);
        }
        __syncthreads();
#pragma unroll
        for (int ks = 0; ks < 2; ks++) {
            half8 av = __builtin_bit_cast(half8, Af[ks * 4 + w][lane]);
#pragma unroll
            for (int j = 0; j < 5; j++) {
                half8 bv = __builtin_bit_cast(half8, Bf[j * 2 + ks][lane]);
                acc[j] = __builtin_amdgcn_mfma_f32_16x16x32_f16(av, bv, acc[j], 0, 0, 0);
            }
        }
        __syncthreads();
    }
    const int r0 = (lane >> 4) * 4, cn = lane & 15;
    const int row = m0 + w * 16 + r0;
#pragma unroll
    for (int j = 0; j < 5; j++)
#pragma unroll
        for (int r = 0; r < 4; r++)
            out[(long)(row + r) * E80 + j * 16 + cn] = acc[j][r];
}

// ---------------------------------------------------------------------------
// delta MFMA GEMM + softplus.
// ---------------------------------------------------------------------------
__global__ __launch_bounds__(256)
void delta_mfma(const float* __restrict__ dbl, const _Float16* __restrict__ dtw,
                const float* __restrict__ dba, const float* __restrict__ dbb,
                _Float16* __restrict__ dlt)
{
    __shared__ uint4 Af[8][64];
    __shared__ uint4 Bf[16][64];
    const int m0 = blockIdx.x * 64;
    const int n0 = blockIdx.y * 128;
    const int z  = blockIdx.z;
    const float* bias = (z >> 1) ? dbb : dba;
    const float* Ab = dbl + (long)z * LQ * E80;
    const _Float16* Wb = dtw + (long)(z >> 1) * DI * 64;
    _Float16* ob = dlt + (long)z * LQ * DI;
    const int tid = threadIdx.x, w = tid >> 6, lane = tid & 63;

#pragma unroll
    for (int i = 0; i < 2; i++) {
        int s = tid + i * 256;
        int f = s >> 6, ln = s & 63;
        int mt = f >> 1, ks = f & 1;
        int row = m0 + mt * 16 + (ln & 15);
        int koff = ks * 32 + (ln >> 4) * 8;
        uint4 o = {0u, 0u, 0u, 0u};
        if (koff < 48) {
            const float* p = Ab + (long)row * E80 + koff;
            float4 v0 = *(const float4*)p;
            float4 v1 = *(const float4*)(p + 4);
            o.x = f2h_bits(v0.x) | ((unsigned)f2h_bits(v0.y) << 16);
            o.y = f2h_bits(v0.z) | ((unsigned)f2h_bits(v0.w) << 16);
            o.z = f2h_bits(v1.x) | ((unsigned)f2h_bits(v1.y) << 16);
            o.w = f2h_bits(v1.z) | ((unsigned)f2h_bits(v1.w) << 16);
        }
        Af[f][ln] = o;
    }
#pragma unroll
    for (int i = 0; i < 4; i++) {
        int s = tid + i * 256;
        int f = s >> 6, ln = s & 63;
        int nt = f >> 1, ks = f & 1;
        int d = n0 + nt * 16 + (ln & 15);
        int koff = ks * 32 + (ln >> 4) * 8;
        Bf[f][ln] = *(const uint4*)(Wb + (long)d * 64 + koff);
    }
    __syncthreads();

    f32x4 acc[8];
#pragma unroll
    for (int j = 0; j < 8; j++) acc[j] = {0.f, 0.f, 0.f, 0.f};
#pragma unroll
    for (int ks = 0; ks < 2; ks++) {
        half8 av = __builtin_bit_cast(half8, Af[w * 2 + ks][lane]);
#pragma unroll
        for (int j = 0; j < 8; j++) {
            half8 bv = __builtin_bit_cast(half8, Bf[j * 2 + ks][lane]);
            acc[j] = __builtin_amdgcn_mfma_f32_16x16x32_f16(av, bv, acc[j], 0, 0, 0);
        }
    }
    const int r0 = (lane >> 4) * 4, cn = lane & 15;
    const int row = m0 + w * 16 + r0;
#pragma unroll
    for (int j = 0; j < 8; j++) {
        int d = n0 + j * 16 + cn;
        float bi = bias[d];
#pragma unroll
        for (int r = 0; r < 4; r++) {
            float a = acc[j][r] + bi;
            float sp = (a > 20.f) ? a : log1pf(__expf(a));
            ob[(long)(row + r) * DI + d] = (_Float16)sp;
        }
    }
}

// ---------------------------------------------------------------------------
// Transpose z-half of xz [b][DI..2DI][l] -> z_t fp16 [b][l][d].
// ---------------------------------------------------------------------------
__global__ __launch_bounds__(256)
void transpose_z(const float* __restrict__ xz, _Float16* __restrict__ zt)
{
    __shared__ float t[64][65];
    const int l0 = blockIdx.x * 64, d0 = blockIdx.y * 64, b = blockIdx.z;
    const float* src = xz + ((long)b * 2 * DI + DI + d0) * LQ + l0;
    const int tid = threadIdx.x;
    const int r = tid >> 4, c4 = (tid & 15) * 4;
#pragma unroll
    for (int i = 0; i < 4; i++) {
        float4 v = *(const float4*)&src[(long)(r + i * 16) * LQ + c4];
        t[c4 + 0][r + i * 16] = v.x; t[c4 + 1][r + i * 16] = v.y;
        t[c4 + 2][r + i * 16] = v.z; t[c4 + 3][r + i * 16] = v.w;
    }
    __syncthreads();
    const int l = tid >> 2, seg = (tid & 3) * 16;
    ushort tmp[16];
#pragma unroll
    for (int j = 0; j < 16; j++) tmp[j] = f2h_bits(t[l][seg + j]);
    uint4 p0, p1;
    p0.x = tmp[0] | (tmp[1] << 16);  p0.y = tmp[2] | (tmp[3] << 16);
    p0.z = tmp[4] | (tmp[5] << 16);  p0.w = tmp[6] | (tmp[7] << 16);
    p1.x = tmp[8] | (tmp[9] << 16);  p1.y = tmp[10] | (tmp[11] << 16);
    p1.z = tmp[12] | (tmp[13] << 16); p1.w = tmp[14] | (tmp[15] << 16);
    ushort* dst = (ushort*)(zt + ((long)b * LQ + l0 + l) * DI + d0 + seg);
    *(uint4*)dst = p0;
    *(uint4*)(dst + 8) = p1;
}

// ---------------------------------------------------------------------------
// Scan pass 1: per-chunk summaries (lane = channel, 16 states in VGPRs).
// Fast path: A[d][n] == -(n+1) (the problem's A_log = log(1..16)) lets
// exp(dl*An[n]) = r^(n+1), r = exp(-dl): 1 exp + 15 muls instead of 16 exps.
// Verified per-thread with tolerance; general fallback otherwise.
// ---------------------------------------------------------------------------
__global__ __launch_bounds__(256)
void scan_p1(const _Float16* __restrict__ ut, const _Float16* __restrict__ dlt,
             const float* __restrict__ dbl,
             const float* __restrict__ Ala, const float* __restrict__ Alb,
             float* __restrict__ Sdl, float* __restrict__ Hloc)
{
    const int d = blockIdx.x * 256 + threadIdx.x;
    const int c = blockIdx.y;
    const int z = blockIdx.z;
    const int br = z >> 1;
    const float* Al = br ? Alb : Ala;
    float An[16];
#pragma unroll
    for (int i = 0; i < 4; i++) {
        float4 v = *(const float4*)&Al[(long)d * 16 + i * 4];
        An[i * 4] = -__expf(v.x); An[i * 4 + 1] = -__expf(v.y);
        An[i * 4 + 2] = -__expf(v.z); An[i * 4 + 3] = -__expf(v.w);
    }
    bool fast = true;
#pragma unroll
    for (int n = 0; n < 16; n++)
        fast = fast && (__builtin_fabsf(An[n] + (float)(n + 1)) < 1e-3f);

    const long lbase = (long)z * LQ + (long)c * CH;
    const _Float16* ub = ut + lbase * DI + d;
    const _Float16* db = dlt + lbase * DI + d;
    const float* bc = dbl + lbase * E80 + 48;

    float h[16];
#pragma unroll
    for (int n = 0; n < 16; n++) h[n] = 0.f;
    float sdl = 0.f;

    for (int t0 = 0; t0 < CH; t0 += 8) {
        _Float16 uu[8], dd[8];
#pragma unroll
        for (int j = 0; j < 8; j++) {
            uu[j] = ub[(long)(t0 + j) * DI];
            dd[j] = db[(long)(t0 + j) * DI];
        }
#pragma unroll
        for (int j = 0; j < 8; j++) {
            float dl = (float)dd[j];
            float u  = (float)uu[j];
            sdl += dl;
            float du = dl * u;
            const float* Bp = bc + (long)(t0 + j) * E80;
            float Bv[16];
#pragma unroll
            for (int i = 0; i < 4; i++) {
                float4 v = *(const float4*)&Bp[i * 4];
                Bv[i * 4] = v.x; Bv[i * 4 + 1] = v.y;
                Bv[i * 4 + 2] = v.z; Bv[i * 4 + 3] = v.w;
            }
            if (fast) {
                float r = __expf(-dl);
                float p = r;
                h[0] = fmaf(p, h[0], du * Bv[0]);
#pragma unroll
                for (int n = 1; n < 16; n++) {
                    p *= r;
                    h[n] = fmaf(p, h[n], du * Bv[n]);
                }
            } else {
#pragma unroll
                for (int n = 0; n < 16; n++)
                    h[n] = fmaf(__expf(dl * An[n]), h[n], du * Bv[n]);
            }
        }
    }
    Sdl[((long)z * NC + c) * DI + d] = sdl;
    float* Hp = Hloc + (((long)z * NC + c) * DI + d) * 16;
#pragma unroll
    for (int i = 0; i < 4; i++)
        *(float4*)&Hp[i * 4] = make_float4(h[i * 4], h[i * 4 + 1], h[i * 4 + 2], h[i * 4 + 3]);
}

// ---------------------------------------------------------------------------
// Scan pass 2: inter-chunk scan.
// ---------------------------------------------------------------------------
__global__ __launch_bounds__(256)
void scan_p2(const float* __restrict__ Sdl, const float* __restrict__ Hloc,
             const float* __restrict__ Ala, const float* __restrict__ Alb,
             float* __restrict__ h0)
{
    const int idx = blockIdx.x * 256 + threadIdx.x;
    const int z = blockIdx.y;
    const int d = idx >> 4, n = idx & 15;
    const float* Al = (z >> 1) ? Alb : Ala;
    const float An = -__expf(Al[(long)d * 16 + n]);
    float h = 0.f;
    for (int c = 0; c < NC; c++) {
        h0[((long)z * NC + c) * DI * 16 + idx] = h;
        float sdl = Sdl[((long)z * NC + c) * DI + d];
        float Hl = Hloc[((long)z * NC + c) * DI * 16 + idx];
        h = fmaf(__expf(An * sdl), h, Hl);
    }
}

// ---------------------------------------------------------------------------
// Scan pass 3: re-run chunks from h0, emit y (+D) fp16 [l][d], B pre-flipped.
// Same fast path as scan_p1.
// ---------------------------------------------------------------------------
__global__ __launch_bounds__(256)
void scan_p3(const _Float16* __restrict__ ut, const _Float16* __restrict__ dlt,
             const float* __restrict__ dbl, const float* __restrict__ h0,
             const float* __restrict__ Ala, const float* __restrict__ Alb,
             const float* __restrict__ Da, const float* __restrict__ Db,
             _Float16* __restrict__ ya, _Float16* __restrict__ yb)
{
    const int d = blockIdx.x * 256 + threadIdx.x;
    const int c = blockIdx.y;
    const int z = blockIdx.z;
    const int br = z >> 1, b = z & 1;
    const float* Al = br ? Alb : Ala;
    float An[16];
#pragma unroll
    for (int i = 0; i < 4; i++) {
        float4 v = *(const float4*)&Al[(long)d * 16 + i * 4];
        An[i * 4] = -__expf(v.x); An[i * 4 + 1] = -__expf(v.y);
        An[i * 4 + 2] = -__expf(v.z); An[i * 4 + 3] = -__expf(v.w);
    }
    bool fast = true;
#pragma unroll
    for (int n = 0; n < 16; n++)
        fast = fast && (__builtin_fabsf(An[n] + (float)(n + 1)) < 1e-3f);

    const float Dd = (br ? Db : Da)[d];
    const long lbase = (long)z * LQ + (long)c * CH;
    const _Float16* ub = ut + lbase * DI + d;
    const _Float16* db = dlt + lbase * DI + d;
    const float* bc = dbl + lbase * E80 + 48;
    const float* Hp = h0 + (((long)z * NC + c) * DI + d) * 16;
    float h[16];
#pragma unroll
    for (int i = 0; i < 4; i++) {
        float4 v = *(const float4*)&Hp[i * 4];
        h[i * 4] = v.x; h[i * 4 + 1] = v.y; h[i * 4 + 2] = v.z; h[i * 4 + 3] = v.w;
    }
    _Float16* yo = br ? yb : ya;

    for (int t0 = 0; t0 < CH; t0 += 8) {
        _Float16 uu[8], dd[8];
#pragma unroll
        for (int j = 0; j < 8; j++) {
            uu[j] = ub[(long)(t0 + j) * DI];
            dd[j] = db[(long)(t0 + j) * DI];
        }
#pragma unroll
        for (int j = 0; j < 8; j++) {
            float dl = (float)dd[j];
            float u  = (float)uu[j];
            float du = dl * u;
            const float* Bp = bc + (long)(t0 + j) * E80;
            float Bv[16], Cv[16];
#pragma unroll
            for (int i = 0; i < 4; i++) {
                float4 v = *(const float4*)&Bp[i * 4];
                Bv[i * 4] = v.x; Bv[i * 4 + 1] = v.y;
                Bv[i * 4 + 2] = v.z; Bv[i * 4 + 3] = v.w;
                float4 w2 = *(const float4*)&Bp[16 + i * 4];
                Cv[i * 4] = w2.x; Cv[i * 4 + 1] = w2.y;
                Cv[i * 4 + 2] = w2.z; Cv[i * 4 + 3] = w2.w;
            }
            float y = u * Dd;
            if (fast) {
                float r = __expf(-dl);
                float p = r;
                h[0] = fmaf(p, h[0], du * Bv[0]);
                y = fmaf(h[0], Cv[0], y);
#pragma unroll
                for (int n = 1; n < 16; n++) {
                    p *= r;
                    h[n] = fmaf(p, h[n], du * Bv[n]);
                    y = fmaf(h[n], Cv[n], y);
                }
            } else {
#pragma unroll
                for (int n = 0; n < 16; n++) {
                    h[n] = fmaf(__expf(dl * An[n]), h[n], du * Bv[n]);
                    y = fmaf(h[n], Cv[n], y);
                }
            }
            int t = c * CH + t0 + j;
            long lorig = br ? (LQ - 1 - t) : t;
            yo[((long)b * LQ + lorig) * DI + d] = (_Float16)y;
        }
    }
}

// ---------------------------------------------------------------------------
// yf = (ya + yb) * silu(z)  -> fp16 [b][l][d]. 8 elements/thread.
// ---------------------------------------------------------------------------
__global__ __launch_bounds__(256)
void fuse_y(const _Float16* __restrict__ ya, const _Float16* __restrict__ yb,
            const _Float16* __restrict__ zt, _Float16* __restrict__ yf)
{
    long i = ((long)blockIdx.x * 256 + threadIdx.x) * 8;
    half8 a = *(const half8*)(ya + i);
    half8 b = *(const half8*)(yb + i);
    half8 zz = *(const half8*)(zt + i);
    half8 o;
#pragma unroll
    for (int j = 0; j < 8; j++) {
        float y = (float)a[j] + (float)b[j];
        float zv = (float)zz[j];
        o[j] = (_Float16)(y * (zv / (1.f + __expf(-zv))));
    }
    *(half8*)(yf + i) = o;
}

// ---------------------------------------------------------------------------
extern "C" void kernel_launch(void* const* d_in, const int* in_sizes, int n_in,
                              void* d_out, int out_size, void* d_ws, size_t ws_size,
                              hipStream_t stream)
{
    const float* hs  = (const float*)d_in[0];
    const float* Wi  = (const float*)d_in[1];
    const float* Wo  = (const float*)d_in[2];
    const float* cwa = (const float*)d_in[3];
    const float* cba = (const float*)d_in[4];
    const float* cwb = (const float*)d_in[5];
    const float* cbb = (const float*)d_in[6];
    const float* xpa = (const float*)d_in[7];
    const float* xpb = (const float*)d_in[8];
    const float* dwa = (const float*)d_in[9];
    const float* dwb = (const float*)d_in[10];
    const float* dba = (const float*)d_in[11];
    const float* dbb = (const float*)d_in[12];
    const float* Ala = (const float*)d_in[13];
    const float* Alb = (const float*)d_in[14];
    const float* Da  = (const float*)d_in[15];
    const float* Db  = (const float*)d_in[16];
    float* out = (float*)d_out;

    float* ws = (float*)d_ws;
    float*    xz   = ws;                                // [0 .. 25165824)
    _Float16* dl_t = (_Float16*)ws;
    _Float16* ya   = (_Float16*)(ws + 12582912);
    _Float16* yb   = (_Float16*)(ws + 18874368);
    float*    dbl  = ws + 25165824;                     // [.. 26476544)
    _Float16* u_t  = (_Float16*)(ws + 26476544);        // [.. 39059456)
    _Float16* yf   = (_Float16*)(ws + 26476544);        // aliases u_t (dead after p3)
    _Float16* z_t  = (_Float16*)(ws + 39059456);        // [.. 45350912)
    float*    Sdl  = ws + 45350912;                     // [.. 45547520)
    float*    Hloc = ws + 45547520;                     // [.. 48693248)
    float*    h0   = ws + 48693248;                     // [.. 51838976)
    _Float16* hsb  = (_Float16*)(ws + 45350912);        // dead pre-scan
    _Float16* Wib  = (_Float16*)(ws + 48496640);        // dead pre-scan
    _Float16* xpw  = (_Float16*)(ws + 49676288);        // dead pre-scan
    _Float16* dtw  = (_Float16*)(ws + 49799168);        // dead pre-scan
    _Float16* Wob  = (_Float16*)(ws + 45350912);        // packed AFTER scan_p3
    // peak footprint: 51,838,976 floats = 207.36 MB (== R3/R6/R8/R9 layout)

    // 0) fp16 packs
    pack_fp16<<<6144, 256, 0, stream>>>(hs, hsb);
    pack_fp16<<<2304, 256, 0, stream>>>(Wi, Wib);
    pack_fp16<<<120, 256, 0, stream>>>(xpa, xpw);
    pack_fp16<<<120, 256, 0, stream>>>(xpb, xpw + 122880);
    pack_dtw<<<12, 256, 0, stream>>>(dwa, dwb, dtw);
    // 1) in_proj (MFMA)
    gemm_mfma<<<dim3(32, 24, 2), 256, 0, stream>>>(
        Wib, hsb, xz, DM, DM, DM, LQ,
        0L, (long)LQ * DM, (long)2 * DI * LQ);
    // 2) conv+silu with transpose -> u_t fp16 [z][l][d]
    conv_silu_t<<<dim3(64, 24, 4), 256, 0, stream>>>(xz, cwa, cba, cwb, cbb, u_t);
    // 3) x_proj (MFMA)
    xproj_mfma<<<dim3(64, 4), 256, 0, stream>>>(u_t, xpw, dbl);
    // 4) z transpose (last reader of xz)
    transpose_z<<<dim3(64, 24, 2), 256, 0, stream>>>(xz, z_t);
    // 5) delta via MFMA + fused softplus (overwrites xz region)
    delta_mfma<<<dim3(64, 12, 4), 256, 0, stream>>>(dbl, dtw, dba, dbb, dl_t);
    // 6) chunked scan
    scan_p1<<<dim3(6, NC, 4), 256, 0, stream>>>(u_t, dl_t, dbl, Ala, Alb, Sdl, Hloc);
    scan_p2<<<dim3(96, 4), 256, 0, stream>>>(Sdl, Hloc, Ala, Alb, h0);
    scan_p3<<<dim3(6, NC, 4), 256, 0, stream>>>(u_t, dl_t, dbl, h0, Ala, Alb, Da, Db, ya, yb);
    // 7) pack Wo (Sdl dead now); fuse (ya+yb)*silu(z)
    pack_fp16<<<1152, 256, 0, stream>>>(Wo, Wob);
    fuse_y<<<6144, 256, 0, stream>>>(ya, yb, z_t, yf);
    // 8) out_proj (MFMA)
    gemm_mfma<<<dim3(6, 32, 2), 256, 0, stream>>>(
        yf, Wob, out, DI, DI, DI, DM,
        (long)LQ * DI, 0L, (long)LQ * DM);
}